// Round 12
// baseline (113.326 us; speedup 1.0000x reference)
//
#include <hip/hip_runtime.h>
#include <math.h>

// Causal attention, B=2 H=16 L=2048 D=64, fp32 in/out, scale=1.
// R12: NO LDS staging — K/V MFMA fragments load directly global->register
// from prepass-formatted arrays (Kh flat f16, VTh transposed f16), 16B/lane.
// Named A/B register double-buffer (tile t+1 loads issue before compute of
// tile t); compiler auto-waitcnt. 1 wave/block, 32 q-rows, KVBLK=32,
// no __syncthreads anywhere in the main loop, LDS = 128B (bc broadcast).
// XCD swizzle: 4 heads pinned per XCD L2. LPT order (long chunks first).
// Swapped-QK^T 32x32 (S^T=mfma(K,Q)), in-register softmax (exp2 domain,
// tree reductions, defer-max THR=8 nats), cvt_pkrtz + 1-shfl P-pack.
// Fallback (ws too small): R5 kernel.

typedef __attribute__((ext_vector_type(8))) _Float16 f16x8;
typedef __attribute__((ext_vector_type(4))) _Float16 f16x4;
typedef __attribute__((ext_vector_type(4))) float f32x4;
typedef __attribute__((ext_vector_type(16))) float f32x16;
typedef unsigned short u16;
typedef unsigned int u32;
typedef __attribute__((ext_vector_type(8))) u16 u16x8;
typedef __attribute__((ext_vector_type(4))) u32 u32x4;

constexpr int Lq = 2048;
constexpr int Dd = 64;
constexpr int KT = 64;   // fallback kernel tile
constexpr int BH = 32;
constexpr float LOG2E = 1.44269504088896f;

// swizzled byte offset inside a [row][128B] LDS tile (fallback kernel only)
#define SWZB(row, bcol) ((((row) * 128) + (bcol)) ^ (((row) & 7) << 4))

static __device__ __forceinline__ u16 f2h(float x) {
  return __builtin_bit_cast(u16, (_Float16)x);
}

static __device__ __forceinline__ float tmax16(const f32x16& v) {
  float a = fmaxf(v[0], v[1]), b = fmaxf(v[2], v[3]);
  float c = fmaxf(v[4], v[5]), d = fmaxf(v[6], v[7]);
  float e = fmaxf(v[8], v[9]), f = fmaxf(v[10], v[11]);
  float g = fmaxf(v[12], v[13]), h = fmaxf(v[14], v[15]);
  a = fmaxf(a, b); c = fmaxf(c, d); e = fmaxf(e, f); g = fmaxf(g, h);
  return fmaxf(fmaxf(a, c), fmaxf(e, g));
}
static __device__ __forceinline__ float tsum16(const f32x16& v) {
  float a = v[0] + v[1], b = v[2] + v[3], c = v[4] + v[5], d = v[6] + v[7];
  float e = v[8] + v[9], f = v[10] + v[11], g = v[12] + v[13], h = v[14] + v[15];
  a += b; c += d; e += f; g += h;
  return (a + c) + (e + g);
}

// ============================ prepass =====================================
constexpr int PREP_KB = (BH * Lq * Dd) / (256 * 16);  // 1024

__global__ __launch_bounds__(256)
void attn_prep(const float* __restrict__ K, const float* __restrict__ V,
               u16* __restrict__ Kh, u16* __restrict__ VTh) {
  const int b = blockIdx.x;
  const int tid = threadIdx.x;
  if (b < PREP_KB) {
    const size_t base = ((size_t)b * 256 + tid) * 16;
    const f32x4* src = reinterpret_cast<const f32x4*>(K + base);
    u16x8 o0, o1;
    #pragma unroll
    for (int i = 0; i < 2; ++i) {
      const f32x4 a = src[i];
      #pragma unroll
      for (int j = 0; j < 4; ++j) o0[i * 4 + j] = f2h(a[j]);
    }
    #pragma unroll
    for (int i = 0; i < 2; ++i) {
      const f32x4 a = src[2 + i];
      #pragma unroll
      for (int j = 0; j < 4; ++j) o1[i * 4 + j] = f2h(a[j]);
    }
    *reinterpret_cast<u16x8*>(Kh + base) = o0;
    *reinterpret_cast<u16x8*>(Kh + base + 8) = o1;
  } else {
    __shared__ u16 lt[64][66];
    const int vb = b - PREP_KB;
    const int h = vb >> 5, tt = vb & 31;
    const float* Vt = V + ((size_t)h * Lq + tt * 64) * Dd;
    const int r = tid & 63, dg = tid >> 6;
    #pragma unroll
    for (int i = 0; i < 4; ++i) {
      const f32x4 a = *reinterpret_cast<const f32x4*>(Vt + (size_t)r * Dd + dg * 16 + i * 4);
      #pragma unroll
      for (int j = 0; j < 2; ++j) {
        const unsigned two =
            (unsigned)f2h(a[2 * j]) | ((unsigned)f2h(a[2 * j + 1]) << 16);
        *reinterpret_cast<unsigned*>(&lt[r][dg * 16 + i * 4 + j * 2]) = two;
      }
    }
    __syncthreads();
    const int d = tid >> 2, kq = tid & 3;
    u16x8 w0, w1;
    #pragma unroll
    for (int j = 0; j < 8; ++j) w0[j] = lt[kq * 16 + j][d];
    #pragma unroll
    for (int j = 0; j < 8; ++j) w1[j] = lt[kq * 16 + 8 + j][d];
    u16* dst = VTh + ((size_t)h * Dd + d) * Lq + tt * 64 + kq * 16;
    *reinterpret_cast<u16x8*>(dst) = w0;
    *reinterpret_cast<u16x8*>(dst + 8) = w1;
  }
}

// ============================ main kernel =================================
// 1 wave/block, 32 q-rows, KVBLK=32; fragments direct from global.
__global__ __launch_bounds__(64)
void attn_main(const float* __restrict__ Q, float* __restrict__ O,
               const u16* __restrict__ Kh, const u16* __restrict__ VTh) {
  __shared__ float bc[32];       // per-q scale/inv broadcast (1 wave: no bar)

  const int lane = threadIdx.x;  // 0..63
  const int l31  = lane & 31;
  const int hi   = lane >> 5;

  // XCD-pinned (bijective, 2048%8==0): XCD x gets swz 256x..256x+255
  // = heads 4x..4x+3; within XCD, chunks descend (LPT).
  const int bid = blockIdx.x;
  const int swz = (bid & 7) * 256 + (bid >> 3);
  const int h     = swz >> 6;        // 0..31
  const int chunk = 63 - (swz & 63); // 0..63

  const float* Qb = Q + (size_t)h * Lq * Dd;
  float*       Ob = O + (size_t)h * Lq * Dd;
  const u16*   Kb = Kh + (size_t)h * Lq * Dd;
  const u16*   Vb = VTh + (size_t)h * Dd * Lq;

  const int T    = chunk + 1;        // 32-key tiles; last is the diagonal
  const int qrow = chunk * 32;

  // ---- Q fragments (B-operand of swapped QK^T), pre-scaled by log2(e):
  // lane holds Q[qrow+l31][kc*16 + hi*8 .. +7]
  f16x8 qf[4];
  #pragma unroll
  for (int kc = 0; kc < 4; ++kc) {
    const float* qp = Qb + (size_t)(qrow + l31) * Dd + kc * 16 + hi * 8;
    const f32x4 a = *reinterpret_cast<const f32x4*>(qp);
    const f32x4 c = *reinterpret_cast<const f32x4*>(qp + 4);
    f16x8 q8;
    #pragma unroll
    for (int e = 0; e < 4; ++e) {
      q8[e]     = (_Float16)(a[e] * LOG2E);
      q8[e + 4] = (_Float16)(c[e] * LOG2E);
    }
    qf[kc] = q8;
  }

  float m = -INFINITY, lsum = 0.f;   // m in log2 units
  f32x16 o0, o1;
  #pragma unroll
  for (int e = 0; e < 16; ++e) { o0[e] = 0.f; o1[e] = 0.f; }

  // Fragment base pointers (per-lane):
  // K-frag (A-op): lane holds K[t*32 + l31][kc*16 + hi*8 ..+7]
  const u16* Krow  = Kb + (size_t)l31 * Dd + hi * 8;
  // V-frag (B-op): lane holds VT[d][t*32 + ks2*16 + hi*8 ..+7], d=l31 / 32+l31
  const u16* V0row = Vb + (size_t)l31 * Lq + hi * 8;
  const u16* V1row = Vb + (size_t)(32 + l31) * Lq + hi * 8;

#define LOADF(kf_, vf_, t_)                                                   \
  do {                                                                        \
    const u16* kp_ = Krow + (size_t)(t_) * 32 * Dd;                           \
    kf_[0] = *reinterpret_cast<const f16x8*>(kp_);                            \
    kf_[1] = *reinterpret_cast<const f16x8*>(kp_ + 16);                       \
    kf_[2] = *reinterpret_cast<const f16x8*>(kp_ + 32);                       \
    kf_[3] = *reinterpret_cast<const f16x8*>(kp_ + 48);                       \
    vf_[0] = *reinterpret_cast<const f16x8*>(V0row + (t_) * 32);              \
    vf_[1] = *reinterpret_cast<const f16x8*>(V0row + (t_) * 32 + 16);         \
    vf_[2] = *reinterpret_cast<const f16x8*>(V1row + (t_) * 32);              \
    vf_[3] = *reinterpret_cast<const f16x8*>(V1row + (t_) * 32 + 16);         \
  } while (0)

#define COMPUTE_TILE(kf_, vf_, last_)                                         \
  do {                                                                        \
    f32x16 st0;                                                               \
    _Pragma("unroll")                                                         \
    for (int e = 0; e < 16; ++e) st0[e] = 0.f;                                \
    __builtin_amdgcn_s_setprio(1);                                            \
    _Pragma("unroll")                                                         \
    for (int kc = 0; kc < 4; ++kc)                                            \
      st0 = __builtin_amdgcn_mfma_f32_32x32x16_f16(kf_[kc], qf[kc], st0,      \
                                                   0, 0, 0);                  \
    __builtin_amdgcn_s_setprio(0);                                            \
    if (last_) {                                                              \
      _Pragma("unroll")                                                       \
      for (int r = 0; r < 16; ++r) {                                          \
        const int crow_ = (r & 3) + 8 * (r >> 2) + 4 * hi;                    \
        if (crow_ > l31) st0[r] = -INFINITY;                                  \
      }                                                                       \
    }                                                                         \
    float pm = tmax16(st0);                                                   \
    pm = fmaxf(pm, __shfl_xor(pm, 32));                                       \
    if (__any(pm > m + 8.f * LOG2E)) {                                        \
      const float mn = fmaxf(m, pm);                                          \
      const float sc = exp2f(m - mn);                                         \
      m = mn;                                                                 \
      lsum *= sc;                                                             \
      if (hi == 0) bc[l31] = sc;                                              \
      const f32x4 s0_ = *reinterpret_cast<const f32x4*>(&bc[4 * hi]);         \
      const f32x4 s1_ = *reinterpret_cast<const f32x4*>(&bc[8 + 4 * hi]);     \
      const f32x4 s2_ = *reinterpret_cast<const f32x4*>(&bc[16 + 4 * hi]);    \
      const f32x4 s3_ = *reinterpret_cast<const f32x4*>(&bc[24 + 4 * hi]);    \
      _Pragma("unroll")                                                       \
      for (int r = 0; r < 16; ++r) {                                          \
        const float fac = (r < 4) ? s0_[r & 3] : (r < 8) ? s1_[r & 3]         \
                        : (r < 12) ? s2_[r & 3] : s3_[r & 3];                 \
        o0[r] *= fac;                                                         \
        o1[r] *= fac;                                                         \
      }                                                                       \
    }                                                                         \
    _Pragma("unroll")                                                         \
    for (int r = 0; r < 16; ++r) st0[r] = exp2f(st0[r] - m);                  \
    float rs = tsum16(st0);                                                   \
    rs += __shfl_xor(rs, 32);                                                 \
    lsum += rs;                                                               \
    _Pragma("unroll")                                                         \
    for (int ks2 = 0; ks2 < 2; ++ks2) {                                       \
      const u32 pe0 = __builtin_bit_cast(u32,                                 \
          __builtin_amdgcn_cvt_pkrtz(st0[8 * ks2 + 0], st0[8 * ks2 + 1]));    \
      const u32 pe1 = __builtin_bit_cast(u32,                                 \
          __builtin_amdgcn_cvt_pkrtz(st0[8 * ks2 + 2], st0[8 * ks2 + 3]));    \
      const u32 po0 = __builtin_bit_cast(u32,                                 \
          __builtin_amdgcn_cvt_pkrtz(st0[8 * ks2 + 4], st0[8 * ks2 + 5]));    \
      const u32 po1 = __builtin_bit_cast(u32,                                 \
          __builtin_amdgcn_cvt_pkrtz(st0[8 * ks2 + 6], st0[8 * ks2 + 7]));    \
      const u32 ss0 = __shfl_xor(hi ? pe0 : po0, 32);                         \
      const u32 ss1 = __shfl_xor(hi ? pe1 : po1, 32);                         \
      u32x4 w_;                                                               \
      w_[0] = hi ? ss0 : pe0;                                                 \
      w_[1] = hi ? ss1 : pe1;                                                 \
      w_[2] = hi ? po0 : ss0;                                                 \
      w_[3] = hi ? po1 : ss1;                                                 \
      const f16x8 pa = __builtin_bit_cast(f16x8, w_);                         \
      __builtin_amdgcn_s_setprio(1);                                          \
      o0 = __builtin_amdgcn_mfma_f32_32x32x16_f16(pa, vf_[ks2], o0, 0, 0, 0); \
      o1 = __builtin_amdgcn_mfma_f32_32x32x16_f16(pa, vf_[2 + ks2], o1,       \
                                                  0, 0, 0);                   \
      __builtin_amdgcn_s_setprio(0);                                          \
    }                                                                         \
  } while (0)

  // ---- named A/B register double-buffer (no runtime-indexed arrays)
  f16x8 kA[4], vA[4], kB[4], vB[4];
  LOADF(kA, vA, 0);
  int t = 0;
  #pragma unroll 1
  while (true) {
    if (t + 1 < T) LOADF(kB, vB, t + 1);
    COMPUTE_TILE(kA, vA, t == T - 1);
    if (++t == T) break;
    if (t + 1 < T) LOADF(kA, vA, t + 1);
    COMPUTE_TILE(kB, vB, t == T - 1);
    if (++t == T) break;
  }

  // ---- epilogue: O /= lsum; per-q inv broadcast via LDS; store fp32
  const float inv = 1.f / lsum;
  if (hi == 0) bc[l31] = inv;
  const f32x4 i0 = *reinterpret_cast<const f32x4*>(&bc[4 * hi]);
  const f32x4 i1 = *reinterpret_cast<const f32x4*>(&bc[8 + 4 * hi]);
  const f32x4 i2 = *reinterpret_cast<const f32x4*>(&bc[16 + 4 * hi]);
  const f32x4 i3 = *reinterpret_cast<const f32x4*>(&bc[24 + 4 * hi]);
  #pragma unroll
  for (int r = 0; r < 16; ++r) {
    const int crow = (r & 3) + 8 * (r >> 2) + 4 * hi;
    const float fac = (r < 4) ? i0[r & 3] : (r < 8) ? i1[r & 3]
                    : (r < 12) ? i2[r & 3] : i3[r & 3];
    float* op = Ob + (size_t)(qrow + crow) * Dd + l31;
    op[0]  = o0[r] * fac;
    op[32] = o1[r] * fac;
  }
#undef LOADF
#undef COMPUTE_TILE
}

// ======================= fallback (R5, no ws needed) ======================
__global__ __launch_bounds__(256)
void causal_attn_fb(const float* __restrict__ Q, const float* __restrict__ K,
                    const float* __restrict__ V, float* __restrict__ O) {
  __shared__ char ks[2][KT * 128];
  __shared__ char vt[2][Dd * 128];
  __shared__ char pl[4][16 * 128];
  const int tid = threadIdx.x, lane = tid & 63, wv = tid >> 6;
  const int l15 = lane & 15, g = lane >> 4;
  const int kg = tid & 15, dq = tid >> 4;
  const int bh = blockIdx.x / 16, pr = blockIdx.x % 16;
  const size_t base = (size_t)bh * Lq * Dd;
  const float* Qb = Q + base; const float* Kb = K + base;
  const float* Vb = V + base; float* Ob = O + base;
  char* pw = pl[wv];
  #pragma unroll 1
  for (int phase = 0; phase < 2; ++phase) {
    const int chunk = (phase == 0) ? pr : (31 - pr);
    const int row0 = chunk * 64, T = chunk + 1, qrow = row0 + wv * 16;
    f16x8 qf[2];
    #pragma unroll
    for (int kk = 0; kk < 2; ++kk) {
      const float* qp = Qb + (size_t)(qrow + l15) * Dd + kk * 32 + g * 8;
      const f32x4 a = *reinterpret_cast<const f32x4*>(qp);
      const f32x4 b = *reinterpret_cast<const f32x4*>(qp + 4);
      f16x8 q8;
      #pragma unroll
      for (int i = 0; i < 4; ++i) { q8[i] = (_Float16)a[i]; q8[i+4] = (_Float16)b[i]; }
      qf[kk] = q8;
    }
    float m[4], lsum[4]; f32x4 o[4];
    #pragma unroll
    for (int r = 0; r < 4; ++r) { m[r] = -INFINITY; lsum[r] = 0.f; }
    #pragma unroll
    for (int nd = 0; nd < 4; ++nd) o[nd] = f32x4{0.f, 0.f, 0.f, 0.f};
    {
      f32x4 kreg[4], vreg[4];
      #pragma unroll
      for (int i = 0; i < 4; ++i) {
        const int c = tid + i * 256;
        kreg[i] = *reinterpret_cast<const f32x4*>(Kb + (size_t)(c >> 4) * Dd + (c & 15) * 4);
      }
      #pragma unroll
      for (int c = 0; c < 4; ++c)
        vreg[c] = *reinterpret_cast<const f32x4*>(Vb + (size_t)(kg * 4 + c) * Dd + dq * 4);
      __syncthreads();
      #pragma unroll
      for (int i = 0; i < 4; ++i) {
        const int c = tid + i * 256;
        f16x4 hh;
        #pragma unroll
        for (int jj = 0; jj < 4; ++jj) hh[jj] = (_Float16)kreg[i][jj];
        *reinterpret_cast<f16x4*>(ks[0] + SWZB(c >> 4, (c & 15) * 8)) = hh;
      }
      #pragma unroll
      for (int jj = 0; jj < 4; ++jj) {
        f16x4 hh;
        #pragma unroll
        for (int c = 0; c < 4; ++c) hh[c] = (_Float16)vreg[c][jj];
        *reinterpret_cast<f16x4*>(vt[0] + SWZB(dq * 4 + jj, kg * 8)) = hh;
      }
    }
    int cur = 0;
    #pragma unroll 1
    for (int t = 0; t < T; ++t) {
      __syncthreads();
      const char* kb = ks[cur]; const char* vb = vt[cur];
      f32x4 kreg[4], vreg[4];
      const bool pfn = (t + 1 < T);
      if (pfn) {
        const float* Kt = Kb + (size_t)(t + 1) * KT * Dd;
        const float* Vt = Vb + (size_t)(t + 1) * KT * Dd;
        #pragma unroll
        for (int i = 0; i < 4; ++i) {
          const int c = tid + i * 256;
          kreg[i] = *reinterpret_cast<const f32x4*>(Kt + (size_t)(c >> 4) * Dd + (c & 15) * 4);
        }
        #pragma unroll
        for (int c = 0; c < 4; ++c)
          vreg[c] = *reinterpret_cast<const f32x4*>(Vt + (size_t)(kg * 4 + c) * Dd + dq * 4);
      }
      f32x4 s[4];
      #pragma unroll
      for (int n = 0; n < 4; ++n) s[n] = f32x4{0.f, 0.f, 0.f, 0.f};
      #pragma unroll
      for (int kk = 0; kk < 2; ++kk) {
        #pragma unroll
        for (int n = 0; n < 4; ++n) {
          const f16x8 kf = *reinterpret_cast<const f16x8*>(kb + SWZB(n * 16 + l15, kk * 64 + g * 16));
          s[n] = __builtin_amdgcn_mfma_f32_16x16x32_f16(qf[kk], kf, s[n], 0, 0, 0);
        }
      }
      if (t == T - 1) {
        #pragma unroll
        for (int n = 0; n < 4; ++n) {
          const int key = t * KT + n * 16 + l15;
          #pragma unroll
          for (int r = 0; r < 4; ++r)
            if (key > qrow + 4 * g + r) s[n][r] = -INFINITY;
        }
      }
      float rmax[4], rsum[4], scale[4];
      #pragma unroll
      for (int r = 0; r < 4; ++r)
        rmax[r] = fmaxf(fmaxf(s[0][r], s[1][r]), fmaxf(s[2][r], s[3][r]));
      #pragma unroll
      for (int mk = 1; mk <= 8; mk <<= 1) {
        #pragma unroll
        for (int r = 0; r < 4; ++r) rmax[r] = fmaxf(rmax[r], __shfl_xor(rmax[r], mk));
      }
      #pragma unroll
      for (int r = 0; r < 4; ++r) {
        const float mn = fmaxf(m[r], rmax[r]);
        scale[r] = __expf(m[r] - mn); m[r] = mn;
      }
      #pragma unroll
      for (int n = 0; n < 4; ++n) {
        #pragma unroll
        for (int r = 0; r < 4; ++r) s[n][r] = __expf(s[n][r] - m[r]);
      }
      #pragma unroll
      for (int r = 0; r < 4; ++r) rsum[r] = (s[0][r] + s[1][r]) + (s[2][r] + s[3][r]);
      #pragma unroll
      for (int mk = 1; mk <= 8; mk <<= 1) {
        #pragma unroll
        for (int r = 0; r < 4; ++r) rsum[r] += __shfl_xor(rsum[r], mk);
      }
      #pragma unroll
      for (int r = 0; r < 4; ++r) lsum[r] = lsum[r] * scale[r] + rsum[r];
      #pragma unroll
      for (int nd = 0; nd < 4; ++nd) {
        #pragma unroll
        for (int r = 0; r < 4; ++r) o[nd][r] *= scale[r];
      }
      #pragma unroll
      for (int n = 0; n < 4; ++n) {
        #pragma unroll
        for (int r = 0; r < 4; ++r)
          *reinterpret_cast<_Float16*>(pw + SWZB(4 * g + r, (n * 16 + l15) * 2)) = (_Float16)s[n][r];
      }
      asm volatile("s_waitcnt lgkmcnt(0)" ::: "memory");
      __builtin_amdgcn_sched_barrier(0);
      #pragma unroll
      for (int kblk = 0; kblk < 2; ++kblk) {
        const f16x8 pf = *reinterpret_cast<const f16x8*>(pw + SWZB(l15, kblk * 64 + g * 16));
        #pragma unroll
        for (int nd = 0; nd < 4; ++nd) {
          const f16x8 vf = *reinterpret_cast<const f16x8*>(vb + SWZB(nd * 16 + l15, kblk * 64 + g * 16));
          o[nd] = __builtin_amdgcn_mfma_f32_16x16x32_f16(pf, vf, o[nd], 0, 0, 0);
        }
      }
      if (pfn) {
        char* kn = ks[cur ^ 1]; char* vn = vt[cur ^ 1];
        #pragma unroll
        for (int i = 0; i < 4; ++i) {
          const int c = tid + i * 256;
          f16x4 hh;
          #pragma unroll
          for (int jj = 0; jj < 4; ++jj) hh[jj] = (_Float16)kreg[i][jj];
          *reinterpret_cast<f16x4*>(kn + SWZB(c >> 4, (c & 15) * 8)) = hh;
        }
        #pragma unroll
        for (int jj = 0; jj < 4; ++jj) {
          f16x4 hh;
          #pragma unroll
          for (int c = 0; c < 4; ++c) hh[c] = (_Float16)vreg[c][jj];
          *reinterpret_cast<f16x4*>(vn + SWZB(dq * 4 + jj, kg * 8)) = hh;
        }
      }
      cur ^= 1;
    }
    float inv[4];
    #pragma unroll
    for (int r = 0; r < 4; ++r) inv[r] = 1.f / lsum[r];
    #pragma unroll
    for (int nd = 0; nd < 4; ++nd) {
      #pragma unroll
      for (int r = 0; r < 4; ++r)
        Ob[(size_t)(qrow + 4 * g + r) * Dd + nd * 16 + l15] = o[nd][r] * inv[r];
    }
  }
}

extern "C" void kernel_launch(void* const* d_in, const int* in_sizes, int n_in,
                              void* d_out, int out_size, void* d_ws, size_t ws_size,
                              hipStream_t stream) {
  const float* q = (const float*)d_in[0];
  const float* k = (const float*)d_in[1];
  const float* v = (const float*)d_in[2];
  float* o = (float*)d_out;
  const size_t elems = (size_t)BH * Lq * Dd;
  const size_t need = elems * 2 * 2;  // Kh + VTh, f16
  if (ws_size >= need) {
    u16* Kh = (u16*)d_ws;
    u16* VTh = Kh + elems;
    attn_prep<<<dim3(2 * PREP_KB), dim3(256), 0, stream>>>(k, v, Kh, VTh);
    attn_main<<<dim3(BH * 64), dim3(64), 0, stream>>>(q, o, Kh, VTh);
  } else {
    causal_attn_fb<<<dim3(BH * 16), dim3(256), 0, stream>>>(q, k, v, o);
  }
  (void)in_sizes; (void)n_in; (void)out_size;
}

// Round 13
// 86.743 us; speedup vs baseline: 1.3065x; 1.3065x over previous
//
#include <hip/hip_runtime.h>
#include <math.h>

// Causal attention, B=2 H=16 L=2048 D=64, fp32 in/out, scale=1.
// R13 = R8 skeleton EXACTLY (2-wave blocks, 32x32 swapped-QK^T, head-grouped
// 4-round balanced mapping, global_load_lds staging, dbuf, 64-key tiles)
// + verified micro-opts only (LPT dispatch REMOVED -- R10's regression):
//  - exp2 domain (qf pre-scaled by log2e; bare v_exp), THR = 8*log2e
//  - depth-5 tree max/sum reductions
//  - single-shuffle P-pack (8 shfl/tile)
//  - hoisted zero vector as C-operand of first MFMA (kills 32 v_mov/tile)
// Fallback (ws too small): R5 kernel.

typedef __attribute__((ext_vector_type(8))) _Float16 f16x8;
typedef __attribute__((ext_vector_type(4))) _Float16 f16x4;
typedef __attribute__((ext_vector_type(4))) float f32x4;
typedef __attribute__((ext_vector_type(16))) float f32x16;
typedef unsigned short u16;
typedef unsigned int u32;
typedef __attribute__((ext_vector_type(8))) u16 u16x8;
typedef __attribute__((ext_vector_type(4))) u32 u32x4;

constexpr int Lq = 2048;
constexpr int Dd = 64;
constexpr int KT = 64;
constexpr int BH = 32;
constexpr float LOG2E = 1.44269504088896f;

// swizzled byte offset inside a [row][128B] LDS tile
#define SWZB(row, bcol) ((((row) * 128) + (bcol)) ^ (((row) & 7) << 4))

#define GLOAD_LDS16(g, l)                                                     \
  __builtin_amdgcn_global_load_lds(                                           \
      (const __attribute__((address_space(1))) void*)(g),                     \
      (__attribute__((address_space(3))) void*)(l), 16, 0, 0)

static __device__ __forceinline__ u16 f2h(float x) {
  return __builtin_bit_cast(u16, (_Float16)x);
}

static __device__ __forceinline__ float tmax16(const f32x16& v) {
  float a = fmaxf(v[0], v[1]), b = fmaxf(v[2], v[3]);
  float c = fmaxf(v[4], v[5]), d = fmaxf(v[6], v[7]);
  float e = fmaxf(v[8], v[9]), f = fmaxf(v[10], v[11]);
  float g = fmaxf(v[12], v[13]), h = fmaxf(v[14], v[15]);
  a = fmaxf(a, b); c = fmaxf(c, d); e = fmaxf(e, f); g = fmaxf(g, h);
  return fmaxf(fmaxf(a, c), fmaxf(e, g));
}
static __device__ __forceinline__ float tsum16(const f32x16& v) {
  float a = v[0] + v[1], b = v[2] + v[3], c = v[4] + v[5], d = v[6] + v[7];
  float e = v[8] + v[9], f = v[10] + v[11], g = v[12] + v[13], h = v[14] + v[15];
  a += b; c += d; e += f; g += h;
  return (a + c) + (e + g);
}

// ============================ prepass =====================================
constexpr int PREP_KB = (BH * Lq * Dd) / (256 * 16);  // 1024

__global__ __launch_bounds__(256)
void attn_prep(const float* __restrict__ K, const float* __restrict__ V,
               u16* __restrict__ Kh, u16* __restrict__ VTh) {
  const int b = blockIdx.x;
  const int tid = threadIdx.x;
  if (b < PREP_KB) {
    const size_t base = ((size_t)b * 256 + tid) * 16;
    const f32x4* src = reinterpret_cast<const f32x4*>(K + base);
    u16x8 o0, o1;
    #pragma unroll
    for (int i = 0; i < 2; ++i) {
      const f32x4 a = src[i];
      #pragma unroll
      for (int j = 0; j < 4; ++j) o0[i * 4 + j] = f2h(a[j]);
    }
    #pragma unroll
    for (int i = 0; i < 2; ++i) {
      const f32x4 a = src[2 + i];
      #pragma unroll
      for (int j = 0; j < 4; ++j) o1[i * 4 + j] = f2h(a[j]);
    }
    *reinterpret_cast<u16x8*>(Kh + base) = o0;
    *reinterpret_cast<u16x8*>(Kh + base + 8) = o1;
  } else {
    __shared__ u16 lt[64][66];
    const int vb = b - PREP_KB;
    const int h = vb >> 5, tt = vb & 31;
    const float* Vt = V + ((size_t)h * Lq + tt * 64) * Dd;
    const int r = tid & 63, dg = tid >> 6;
    #pragma unroll
    for (int i = 0; i < 4; ++i) {
      const f32x4 a = *reinterpret_cast<const f32x4*>(Vt + (size_t)r * Dd + dg * 16 + i * 4);
      #pragma unroll
      for (int j = 0; j < 2; ++j) {
        const unsigned two =
            (unsigned)f2h(a[2 * j]) | ((unsigned)f2h(a[2 * j + 1]) << 16);
        *reinterpret_cast<unsigned*>(&lt[r][dg * 16 + i * 4 + j * 2]) = two;
      }
    }
    __syncthreads();
    const int d = tid >> 2, kq = tid & 3;
    u16x8 w0, w1;
    #pragma unroll
    for (int j = 0; j < 8; ++j) w0[j] = lt[kq * 16 + j][d];
    #pragma unroll
    for (int j = 0; j < 8; ++j) w1[j] = lt[kq * 16 + 8 + j][d];
    u16* dst = VTh + ((size_t)h * Dd + d) * Lq + tt * 64 + kq * 16;
    *reinterpret_cast<u16x8*>(dst) = w0;
    *reinterpret_cast<u16x8*>(dst + 8) = w1;
  }
}

// ============================ main kernel =================================
// 2 waves/block, 32 q-rows/wave, one 64-row chunk per block.
__global__ __launch_bounds__(128)
void attn_main(const float* __restrict__ Q, float* __restrict__ O,
               const u16* __restrict__ Kh, const u16* __restrict__ VTh) {
  __shared__ char ks[2][8192];   // K tile [key][d] f16, swizzled, dbuf
  __shared__ char vt2[2][8192];  // VT tile [d][key] f16, swizzled, dbuf
  __shared__ float bc[2][32];    // per-wave scale/inv broadcast

  const int tid  = threadIdx.x;
  const int lane = tid & 63;
  const int wv   = tid >> 6;   // 0..1
  const int l31  = lane & 31;
  const int hi   = lane >> 5;

  // R8's statically balanced, head-grouped mapping (weight 66/slot):
  const int b = blockIdx.x;
  const int j = b >> 8;
  const int i = b & 255;
  const int h = i >> 3;
  const int p = i & 7;
  const int chunk = (j == 0) ? p : (j == 1) ? (31 - p) : (j == 2) ? (p + 8) : (23 - p);

  const float* Qb = Q + (size_t)h * Lq * Dd;
  float*       Ob = O + (size_t)h * Lq * Dd;
  const u16*   Kb = Kh + (size_t)h * Lq * Dd;
  const u16*   Vb = VTh + (size_t)h * Dd * Lq;

  const int row0 = chunk * 64;
  const int T    = chunk + 1;      // 64-key tiles; last is the diagonal
  const int qrow = row0 + wv * 32;

  // ---- Q fragments (B-operand of swapped QK^T), pre-scaled by log2(e):
  // lane holds Q[qrow+l31][kc*16 + hi*8 .. +7]
  f16x8 qf[4];
  #pragma unroll
  for (int kc = 0; kc < 4; ++kc) {
    const float* qp = Qb + (size_t)(qrow + l31) * Dd + kc * 16 + hi * 8;
    const f32x4 a = *reinterpret_cast<const f32x4*>(qp);
    const f32x4 c = *reinterpret_cast<const f32x4*>(qp + 4);
    f16x8 q8;
    #pragma unroll
    for (int e = 0; e < 4; ++e) {
      q8[e]     = (_Float16)(a[e] * LOG2E);
      q8[e + 4] = (_Float16)(c[e] * LOG2E);
    }
    qf[kc] = q8;
  }

  float m = -INFINITY, lsum = 0.f;   // m in log2 units
  f32x16 o0, o1, z16;
  #pragma unroll
  for (int e = 0; e < 16; ++e) { o0[e] = 0.f; o1[e] = 0.f; z16[e] = 0.f; }
  asm volatile("" : "+v"(z16));  // keep the hoisted zero vector live

  // staging geometry (verified R8): LDS slot = wv*256 + it*64 + lane,
  // row = wv*32 + it*8 + (lane>>3), global col-slot = (lane&7) ^ (row&7)
  const int rr = lane >> 3;
  const int c0 = (lane & 7) ^ rr;

  #pragma unroll
  for (int it = 0; it < 4; ++it) {
    const int row = wv * 32 + it * 8 + rr;
    GLOAD_LDS16(Kb + (size_t)row * Dd + c0 * 8,
                &ks[0][wv * 4096 + it * 1024 + lane * 16]);
    GLOAD_LDS16(Vb + (size_t)row * Lq + c0 * 8,
                &vt2[0][wv * 4096 + it * 1024 + lane * 16]);
  }

  int cur = 0;
  #pragma unroll 1
  for (int t = 0; t < T; ++t) {
    __syncthreads();  // drains DMA: tile t resident in buf[cur]
    if (t + 1 < T) {  // prefetch next tile
      #pragma unroll
      for (int it = 0; it < 4; ++it) {
        const int row = wv * 32 + it * 8 + rr;
        GLOAD_LDS16(Kb + (size_t)((t + 1) * KT + row) * Dd + c0 * 8,
                    &ks[cur ^ 1][wv * 4096 + it * 1024 + lane * 16]);
        GLOAD_LDS16(Vb + (size_t)row * Lq + (t + 1) * KT + c0 * 8,
                    &vt2[cur ^ 1][wv * 4096 + it * 1024 + lane * 16]);
      }
    }
    const char* kb = ks[cur];
    const char* vb = vt2[cur];
    const bool last  = (t == T - 1);
    const bool have1 = !(last && wv == 0);  // wave0 diag upper subtile: all masked

    // ---- S^T = K Q^T (x log2e): col=q(l31), row=key crow(r,hi)
    f32x16 st0, st1;
    __builtin_amdgcn_s_setprio(1);
    {
      const f16x8 kf0 = *reinterpret_cast<const f16x8*>(kb + SWZB(l31, hi * 16));
      st0 = __builtin_amdgcn_mfma_f32_32x32x16_f16(kf0, qf[0], z16, 0, 0, 0);
      #pragma unroll
      for (int kc = 1; kc < 4; ++kc) {
        const f16x8 kf = *reinterpret_cast<const f16x8*>(
            kb + SWZB(l31, kc * 32 + hi * 16));
        st0 = __builtin_amdgcn_mfma_f32_32x32x16_f16(kf, qf[kc], st0, 0, 0, 0);
      }
    }
    if (have1) {
      const f16x8 kf0 = *reinterpret_cast<const f16x8*>(kb + SWZB(32 + l31, hi * 16));
      st1 = __builtin_amdgcn_mfma_f32_32x32x16_f16(kf0, qf[0], z16, 0, 0, 0);
      #pragma unroll
      for (int kc = 1; kc < 4; ++kc) {
        const f16x8 kf = *reinterpret_cast<const f16x8*>(
            kb + SWZB(32 + l31, kc * 32 + hi * 16));
        st1 = __builtin_amdgcn_mfma_f32_32x32x16_f16(kf, qf[kc], st1, 0, 0, 0);
      }
    }
    __builtin_amdgcn_s_setprio(0);

    // ---- causal mask (diagonal tile): mask iff crow(r,hi) > l31
    if (last) {
      #pragma unroll
      for (int r = 0; r < 16; ++r) {
        const int crow = (r & 3) + 8 * (r >> 2) + 4 * hi;
        if (wv == 0) { if (crow > l31) st0[r] = -INFINITY; }
        else         { if (crow > l31) st1[r] = -INFINITY; }
      }
    }

    // ---- in-register softmax (log2 domain), defer-max THR = 8*log2e
    float pm = tmax16(st0);
    if (have1) pm = fmaxf(pm, tmax16(st1));
    pm = fmaxf(pm, __shfl_xor(pm, 32));

    if (__any(pm > m + 8.f * LOG2E)) {
      const float mn = fmaxf(m, pm);
      const float sc = exp2f(m - mn);  // first tile: exp2(-inf)=0
      m = mn;
      lsum *= sc;
      if (hi == 0) bc[wv][l31] = sc;   // scale indexed by q
      const f32x4 s0 = *reinterpret_cast<const f32x4*>(&bc[wv][4 * hi]);
      const f32x4 s1 = *reinterpret_cast<const f32x4*>(&bc[wv][8 + 4 * hi]);
      const f32x4 s2 = *reinterpret_cast<const f32x4*>(&bc[wv][16 + 4 * hi]);
      const f32x4 s3 = *reinterpret_cast<const f32x4*>(&bc[wv][24 + 4 * hi]);
      #pragma unroll
      for (int r = 0; r < 16; ++r) {
        const float fac = (r < 4) ? s0[r & 3] : (r < 8) ? s1[r & 3]
                        : (r < 12) ? s2[r & 3] : s3[r & 3];
        o0[r] *= fac;
        o1[r] *= fac;
      }
    }

    #pragma unroll
    for (int r = 0; r < 16; ++r) st0[r] = exp2f(st0[r] - m);
    float rs = tsum16(st0);
    if (have1) {
      #pragma unroll
      for (int r = 0; r < 16; ++r) st1[r] = exp2f(st1[r] - m);
      rs += tsum16(st1);
    }
    rs += __shfl_xor(rs, 32);
    lsum += rs;

    // ---- P-pack (cvt_pkrtz; ONE shfl_xor serves both A-frag words) and PV
    #pragma unroll
    for (int ksub = 0; ksub < 2; ++ksub) {
      if (ksub == 1 && !have1) break;
      const f32x16& st = (ksub == 0) ? st0 : st1;
      #pragma unroll
      for (int ks2 = 0; ks2 < 2; ++ks2) {
        const u32 pe0 = __builtin_bit_cast(u32,
            __builtin_amdgcn_cvt_pkrtz(st[8 * ks2 + 0], st[8 * ks2 + 1]));
        const u32 pe1 = __builtin_bit_cast(u32,
            __builtin_amdgcn_cvt_pkrtz(st[8 * ks2 + 2], st[8 * ks2 + 3]));
        const u32 po0 = __builtin_bit_cast(u32,
            __builtin_amdgcn_cvt_pkrtz(st[8 * ks2 + 4], st[8 * ks2 + 5]));
        const u32 po1 = __builtin_bit_cast(u32,
            __builtin_amdgcn_cvt_pkrtz(st[8 * ks2 + 6], st[8 * ks2 + 7]));
        const u32 ss0 = __shfl_xor(hi ? pe0 : po0, 32);
        const u32 ss1 = __shfl_xor(hi ? pe1 : po1, 32);
        u32x4 w;
        w[0] = hi ? ss0 : pe0;
        w[1] = hi ? ss1 : pe1;
        w[2] = hi ? po0 : ss0;
        w[3] = hi ? po1 : ss1;
        const f16x8 pa = __builtin_bit_cast(f16x8, w);
        const int cb = ksub * 64 + ks2 * 32 + hi * 16;  // key-col bytes in VT
        const f16x8 v0 = *reinterpret_cast<const f16x8*>(vb + SWZB(l31, cb));
        const f16x8 v1 = *reinterpret_cast<const f16x8*>(vb + SWZB(32 + l31, cb));
        __builtin_amdgcn_s_setprio(1);
        o0 = __builtin_amdgcn_mfma_f32_32x32x16_f16(pa, v0, o0, 0, 0, 0);
        o1 = __builtin_amdgcn_mfma_f32_32x32x16_f16(pa, v1, o1, 0, 0, 0);
        __builtin_amdgcn_s_setprio(0);
      }
    }
    cur ^= 1;
  }

  // ---- epilogue: O /= lsum; broadcast inv by q via LDS; store fp32
  const float inv = 1.f / lsum;
  if (hi == 0) bc[wv][l31] = inv;
  const f32x4 i0 = *reinterpret_cast<const f32x4*>(&bc[wv][4 * hi]);
  const f32x4 i1 = *reinterpret_cast<const f32x4*>(&bc[wv][8 + 4 * hi]);
  const f32x4 i2 = *reinterpret_cast<const f32x4*>(&bc[wv][16 + 4 * hi]);
  const f32x4 i3 = *reinterpret_cast<const f32x4*>(&bc[wv][24 + 4 * hi]);
  #pragma unroll
  for (int r = 0; r < 16; ++r) {
    const int crow = (r & 3) + 8 * (r >> 2) + 4 * hi;
    const float fac = (r < 4) ? i0[r & 3] : (r < 8) ? i1[r & 3]
                    : (r < 12) ? i2[r & 3] : i3[r & 3];
    float* op = Ob + (size_t)(qrow + crow) * Dd + l31;
    op[0]  = o0[r] * fac;
    op[32] = o1[r] * fac;
  }
}

// ======================= fallback (R5, no ws needed) ======================
__global__ __launch_bounds__(256)
void causal_attn_fb(const float* __restrict__ Q, const float* __restrict__ K,
                    const float* __restrict__ V, float* __restrict__ O) {
  __shared__ char ks[2][KT * 128];
  __shared__ char vt[2][Dd * 128];
  __shared__ char pl[4][16 * 128];
  const int tid = threadIdx.x, lane = tid & 63, wv = tid >> 6;
  const int l15 = lane & 15, g = lane >> 4;
  const int kg = tid & 15, dq = tid >> 4;
  const int bh = blockIdx.x / 16, pr = blockIdx.x % 16;
  const size_t base = (size_t)bh * Lq * Dd;
  const float* Qb = Q + base; const float* Kb = K + base;
  const float* Vb = V + base; float* Ob = O + base;
  char* pw = pl[wv];
  #pragma unroll 1
  for (int phase = 0; phase < 2; ++phase) {
    const int chunk = (phase == 0) ? pr : (31 - pr);
    const int row0 = chunk * 64, T = chunk + 1, qrow = row0 + wv * 16;
    f16x8 qf[2];
    #pragma unroll
    for (int kk = 0; kk < 2; ++kk) {
      const float* qp = Qb + (size_t)(qrow + l15) * Dd + kk * 32 + g * 8;
      const f32x4 a = *reinterpret_cast<const f32x4*>(qp);
      const f32x4 b = *reinterpret_cast<const f32x4*>(qp + 4);
      f16x8 q8;
      #pragma unroll
      for (int i = 0; i < 4; ++i) { q8[i] = (_Float16)a[i]; q8[i+4] = (_Float16)b[i]; }
      qf[kk] = q8;
    }
    float m[4], lsum[4]; f32x4 o[4];
    #pragma unroll
    for (int r = 0; r < 4; ++r) { m[r] = -INFINITY; lsum[r] = 0.f; }
    #pragma unroll
    for (int nd = 0; nd < 4; ++nd) o[nd] = f32x4{0.f, 0.f, 0.f, 0.f};
    {
      f32x4 kreg[4], vreg[4];
      #pragma unroll
      for (int i = 0; i < 4; ++i) {
        const int c = tid + i * 256;
        kreg[i] = *reinterpret_cast<const f32x4*>(Kb + (size_t)(c >> 4) * Dd + (c & 15) * 4);
      }
      #pragma unroll
      for (int c = 0; c < 4; ++c)
        vreg[c] = *reinterpret_cast<const f32x4*>(Vb + (size_t)(kg * 4 + c) * Dd + dq * 4);
      __syncthreads();
      #pragma unroll
      for (int i = 0; i < 4; ++i) {
        const int c = tid + i * 256;
        f16x4 hh;
        #pragma unroll
        for (int jj = 0; jj < 4; ++jj) hh[jj] = (_Float16)kreg[i][jj];
        *reinterpret_cast<f16x4*>(ks[0] + SWZB(c >> 4, (c & 15) * 8)) = hh;
      }
      #pragma unroll
      for (int jj = 0; jj < 4; ++jj) {
        f16x4 hh;
        #pragma unroll
        for (int c = 0; c < 4; ++c) hh[c] = (_Float16)vreg[c][jj];
        *reinterpret_cast<f16x4*>(vt[0] + SWZB(dq * 4 + jj, kg * 8)) = hh;
      }
    }
    int cur = 0;
    #pragma unroll 1
    for (int t = 0; t < T; ++t) {
      __syncthreads();
      const char* kb = ks[cur]; const char* vb = vt[cur];
      f32x4 kreg[4], vreg[4];
      const bool pfn = (t + 1 < T);
      if (pfn) {
        const float* Kt = Kb + (size_t)(t + 1) * KT * Dd;
        const float* Vt = Vb + (size_t)(t + 1) * KT * Dd;
        #pragma unroll
        for (int i = 0; i < 4; ++i) {
          const int c = tid + i * 256;
          kreg[i] = *reinterpret_cast<const f32x4*>(Kt + (size_t)(c >> 4) * Dd + (c & 15) * 4);
        }
        #pragma unroll
        for (int c = 0; c < 4; ++c)
          vreg[c] = *reinterpret_cast<const f32x4*>(Vt + (size_t)(kg * 4 + c) * Dd + dq * 4);
      }
      f32x4 s[4];
      #pragma unroll
      for (int n = 0; n < 4; ++n) s[n] = f32x4{0.f, 0.f, 0.f, 0.f};
      #pragma unroll
      for (int kk = 0; kk < 2; ++kk) {
        #pragma unroll
        for (int n = 0; n < 4; ++n) {
          const f16x8 kf = *reinterpret_cast<const f16x8*>(kb + SWZB(n * 16 + l15, kk * 64 + g * 16));
          s[n] = __builtin_amdgcn_mfma_f32_16x16x32_f16(qf[kk], kf, s[n], 0, 0, 0);
        }
      }
      if (t == T - 1) {
        #pragma unroll
        for (int n = 0; n < 4; ++n) {
          const int key = t * KT + n * 16 + l15;
          #pragma unroll
          for (int r = 0; r < 4; ++r)
            if (key > qrow + 4 * g + r) s[n][r] = -INFINITY;
        }
      }
      float rmax[4], rsum[4], scale[4];
      #pragma unroll
      for (int r = 0; r < 4; ++r)
        rmax[r] = fmaxf(fmaxf(s[0][r], s[1][r]), fmaxf(s[2][r], s[3][r]));
      #pragma unroll
      for (int mk = 1; mk <= 8; mk <<= 1) {
        #pragma unroll
        for (int r = 0; r < 4; ++r) rmax[r] = fmaxf(rmax[r], __shfl_xor(rmax[r], mk));
      }
      #pragma unroll
      for (int r = 0; r < 4; ++r) {
        const float mn = fmaxf(m[r], rmax[r]);
        scale[r] = __expf(m[r] - mn); m[r] = mn;
      }
      #pragma unroll
      for (int n = 0; n < 4; ++n) {
        #pragma unroll
        for (int r = 0; r < 4; ++r) s[n][r] = __expf(s[n][r] - m[r]);
      }
      #pragma unroll
      for (int r = 0; r < 4; ++r) rsum[r] = (s[0][r] + s[1][r]) + (s[2][r] + s[3][r]);
      #pragma unroll
      for (int mk = 1; mk <= 8; mk <<= 1) {
        #pragma unroll
        for (int r = 0; r < 4; ++r) rsum[r] += __shfl_xor(rsum[r], mk);
      }
      #pragma unroll
      for (int r = 0; r < 4; ++r) lsum[r] = lsum[r] * scale[r] + rsum[r];
      #pragma unroll
      for (int nd = 0; nd < 4; ++nd) {
        #pragma unroll
        for (int r = 0; r < 4; ++r) o[nd][r] *= scale[r];
      }
      #pragma unroll
      for (int n = 0; n < 4; ++n) {
        #pragma unroll
        for (int r = 0; r < 4; ++r)
          *reinterpret_cast<_Float16*>(pw + SWZB(4 * g + r, (n * 16 + l15) * 2)) = (_Float16)s[n][r];
      }
      asm volatile("s_waitcnt lgkmcnt(0)" ::: "memory");
      __builtin_amdgcn_sched_barrier(0);
      #pragma unroll
      for (int kblk = 0; kblk < 2; ++kblk) {
        const f16x8 pf = *reinterpret_cast<const f16x8*>(pw + SWZB(l15, kblk * 64 + g * 16));
        #pragma unroll
        for (int nd = 0; nd < 4; ++nd) {
          const f16x8 vf = *reinterpret_cast<const f16x8*>(vb + SWZB(nd * 16 + l15, kblk * 64 + g * 16));
          o[nd] = __builtin_amdgcn_mfma_f32_16x16x32_f16(pf, vf, o[nd], 0, 0, 0);
        }
      }
      if (pfn) {
        char* kn = ks[cur ^ 1]; char* vn = vt[cur ^ 1];
        #pragma unroll
        for (int i = 0; i < 4; ++i) {
          const int c = tid + i * 256;
          f16x4 hh;
          #pragma unroll
          for (int jj = 0; jj < 4; ++jj) hh[jj] = (_Float16)kreg[i][jj];
          *reinterpret_cast<f16x4*>(kn + SWZB(c >> 4, (c & 15) * 8)) = hh;
        }
        #pragma unroll
        for (int jj = 0; jj < 4; ++jj) {
          f16x4 hh;
          #pragma unroll
          for (int c = 0; c < 4; ++c) hh[c] = (_Float16)vreg[c][jj];
          *reinterpret_cast<f16x4*>(vn + SWZB(dq * 4 + jj, kg * 8)) = hh;
        }
      }
      cur ^= 1;
    }
    float inv[4];
    #pragma unroll
    for (int r = 0; r < 4; ++r) inv[r] = 1.f / lsum[r];
    #pragma unroll
    for (int nd = 0; nd < 4; ++nd) {
      #pragma unroll
      for (int r = 0; r < 4; ++r)
        Ob[(size_t)(qrow + 4 * g + r) * Dd + nd * 16 + l15] = o[nd][r] * inv[r];
    }
  }
}

extern "C" void kernel_launch(void* const* d_in, const int* in_sizes, int n_in,
                              void* d_out, int out_size, void* d_ws, size_t ws_size,
                              hipStream_t stream) {
  const float* q = (const float*)d_in[0];
  const float* k = (const float*)d_in[1];
  const float* v = (const float*)d_in[2];
  float* o = (float*)d_out;
  const size_t elems = (size_t)BH * Lq * Dd;
  const size_t need = elems * 2 * 2;  // Kh + VTh, f16
  if (ws_size >= need) {
    u16* Kh = (u16*)d_ws;
    u16* VTh = Kh + elems;
    attn_prep<<<dim3(2 * PREP_KB), dim3(256), 0, stream>>>(k, v, Kh, VTh);
    attn_main<<<dim3(BH * 32), dim3(128), 0, stream>>>(q, o, Kh, VTh);
  } else {
    causal_attn_fb<<<dim3(BH * 16), dim3(256), 0, stream>>>(q, k, v, o);
  }
  (void)in_sizes; (void)n_in; (void)out_size;
}

// Round 14
// 78.714 us; speedup vs baseline: 1.4397x; 1.1020x over previous
//
#include <hip/hip_runtime.h>
#include <math.h>

// Causal attention, B=2 H=16 L=2048 D=64, fp32 in/out, scale=1.
// R14 = EXACT R8 revert (measured best: 78.8us total, main 71.2us).
// R10/R13 proved the micro-opt bundle (trees/exp2/1-shfl/z16) regresses
// this latency-bound kernel (+6-9us, VGPR 100->112, VALUBusy up); the
// compiler's schedule of this source is the empirical optimum found.
// Structure: swapped-QK^T 32x32 (S^T = mfma(K,Q)) -> full q-row in-lane ->
// in-register softmax (1 shfl_xor(32), no P-LDS round-trip); P->A-frags via
// cvt_pkrtz + shfl_xor(32); defer-max THR=8 with LDS scale broadcast.
// 2-wave blocks (128 thr), 32 q-rows/wave, KVBLK=64, 1024 statically
// balanced blocks (chunk groups {p,31-p,p+8,23-p}: weight 66/slot).
// Prepass (K->f16, VT->f16) + global_load_lds(16) staging.
// Fallback (ws too small): R5 kernel.

typedef __attribute__((ext_vector_type(8))) _Float16 f16x8;
typedef __attribute__((ext_vector_type(4))) _Float16 f16x4;
typedef __attribute__((ext_vector_type(2))) _Float16 f16x2;
typedef __attribute__((ext_vector_type(4))) float f32x4;
typedef __attribute__((ext_vector_type(16))) float f32x16;
typedef unsigned short u16;
typedef unsigned int u32;
typedef __attribute__((ext_vector_type(8))) u16 u16x8;
typedef __attribute__((ext_vector_type(4))) u32 u32x4;

constexpr int Lq = 2048;
constexpr int Dd = 64;
constexpr int KT = 64;
constexpr int BH = 32;

// swizzled byte offset inside a [row][128B] LDS tile
#define SWZB(row, bcol) ((((row) * 128) + (bcol)) ^ (((row) & 7) << 4))

#define GLOAD_LDS16(g, l)                                                     \
  __builtin_amdgcn_global_load_lds(                                           \
      (const __attribute__((address_space(1))) void*)(g),                     \
      (__attribute__((address_space(3))) void*)(l), 16, 0, 0)

static __device__ __forceinline__ u16 f2h(float x) {
  return __builtin_bit_cast(u16, (_Float16)x);
}

// ============================ prepass =====================================
// blocks [0, 1024): K fp32 -> f16 flat (16 elems/thread)
// blocks [1024, 2048): V -> VT f16 [h][d][key], 64x64 tile transpose via LDS
constexpr int PREP_KB = (BH * Lq * Dd) / (256 * 16);  // 1024

__global__ __launch_bounds__(256)
void attn_prep(const float* __restrict__ K, const float* __restrict__ V,
               u16* __restrict__ Kh, u16* __restrict__ VTh) {
  const int b = blockIdx.x;
  const int tid = threadIdx.x;
  if (b < PREP_KB) {
    const size_t base = ((size_t)b * 256 + tid) * 16;
    const f32x4* src = reinterpret_cast<const f32x4*>(K + base);
    u16x8 o0, o1;
    #pragma unroll
    for (int i = 0; i < 2; ++i) {
      const f32x4 a = src[i];
      #pragma unroll
      for (int j = 0; j < 4; ++j) o0[i * 4 + j] = f2h(a[j]);
    }
    #pragma unroll
    for (int i = 0; i < 2; ++i) {
      const f32x4 a = src[2 + i];
      #pragma unroll
      for (int j = 0; j < 4; ++j) o1[i * 4 + j] = f2h(a[j]);
    }
    *reinterpret_cast<u16x8*>(Kh + base) = o0;
    *reinterpret_cast<u16x8*>(Kh + base + 8) = o1;
  } else {
    __shared__ u16 lt[64][66];  // +2 pad -> conflict-free transpose
    const int vb = b - PREP_KB;
    const int h = vb >> 5, tt = vb & 31;
    const float* Vt = V + ((size_t)h * Lq + tt * 64) * Dd;
    const int r = tid & 63, dg = tid >> 6;
    #pragma unroll
    for (int i = 0; i < 4; ++i) {
      const f32x4 a = *reinterpret_cast<const f32x4*>(Vt + (size_t)r * Dd + dg * 16 + i * 4);
      #pragma unroll
      for (int j = 0; j < 2; ++j) {
        const unsigned two =
            (unsigned)f2h(a[2 * j]) | ((unsigned)f2h(a[2 * j + 1]) << 16);
        *reinterpret_cast<unsigned*>(&lt[r][dg * 16 + i * 4 + j * 2]) = two;
      }
    }
    __syncthreads();
    const int d = tid >> 2, kq = tid & 3;
    u16x8 w0, w1;
    #pragma unroll
    for (int j = 0; j < 8; ++j) w0[j] = lt[kq * 16 + j][d];
    #pragma unroll
    for (int j = 0; j < 8; ++j) w1[j] = lt[kq * 16 + 8 + j][d];
    u16* dst = VTh + ((size_t)h * Dd + d) * Lq + tt * 64 + kq * 16;
    *reinterpret_cast<u16x8*>(dst) = w0;
    *reinterpret_cast<u16x8*>(dst + 8) = w1;
  }
}

// ============================ main kernel =================================
// 2 waves/block, 32 q-rows/wave, one 64-row chunk per block.
__global__ __launch_bounds__(128)
void attn_main(const float* __restrict__ Q, float* __restrict__ O,
               const u16* __restrict__ Kh, const u16* __restrict__ VTh) {
  __shared__ char ks[2][8192];   // K tile [key][d] f16, swizzled, dbuf
  __shared__ char vt2[2][8192];  // VT tile [d][key] f16, swizzled, dbuf
  __shared__ float bc[2][32];    // per-wave scale/inv broadcast

  const int tid  = threadIdx.x;
  const int lane = tid & 63;
  const int wv   = tid >> 6;   // 0..1
  const int l31  = lane & 31;
  const int hi   = lane >> 5;

  // statically balanced mapping: 4 rounds j, slot i -> chunk group sums 66
  const int b = blockIdx.x;
  const int j = b >> 8;
  const int i = b & 255;
  const int h = i >> 3;
  const int p = i & 7;
  const int chunk = (j == 0) ? p : (j == 1) ? (31 - p) : (j == 2) ? (p + 8) : (23 - p);

  const float* Qb = Q + (size_t)h * Lq * Dd;
  float*       Ob = O + (size_t)h * Lq * Dd;
  const u16*   Kb = Kh + (size_t)h * Lq * Dd;
  const u16*   Vb = VTh + (size_t)h * Dd * Lq;

  const int row0 = chunk * 64;
  const int T    = chunk + 1;      // 64-key tiles; last is the diagonal
  const int qrow = row0 + wv * 32;

  // ---- Q fragments (B-operand of swapped QK^T):
  // lane holds Q[qrow+l31][kc*16 + hi*8 .. +7]
  f16x8 qf[4];
  #pragma unroll
  for (int kc = 0; kc < 4; ++kc) {
    const float* qp = Qb + (size_t)(qrow + l31) * Dd + kc * 16 + hi * 8;
    const f32x4 a = *reinterpret_cast<const f32x4*>(qp);
    const f32x4 c = *reinterpret_cast<const f32x4*>(qp + 4);
    f16x8 q8;
    #pragma unroll
    for (int e = 0; e < 4; ++e) {
      q8[e]     = (_Float16)a[e];
      q8[e + 4] = (_Float16)c[e];
    }
    qf[kc] = q8;
  }

  float m = -INFINITY, lsum = 0.f;
  f32x16 o0, o1;
  #pragma unroll
  for (int e = 0; e < 16; ++e) { o0[e] = 0.f; o1[e] = 0.f; }

  // staging geometry: LDS slot s = wv*256 + it*64 + lane (16B units);
  // row = s>>3, global col-slot = (lane&7) ^ (row&7); row&7 == lane>>3.
  const int rr = lane >> 3;
  const int c0 = (lane & 7) ^ rr;

  // ---- prologue: tile 0 -> buf 0
  #pragma unroll
  for (int it = 0; it < 4; ++it) {
    const int row = wv * 32 + it * 8 + rr;
    GLOAD_LDS16(Kb + (size_t)row * Dd + c0 * 8,
                &ks[0][wv * 4096 + it * 1024 + lane * 16]);
    GLOAD_LDS16(Vb + (size_t)row * Lq + c0 * 8,
                &vt2[0][wv * 4096 + it * 1024 + lane * 16]);
  }

  int cur = 0;
  #pragma unroll 1
  for (int t = 0; t < T; ++t) {
    __syncthreads();  // drains DMA: tile t resident in buf[cur]
    if (t + 1 < T) {  // prefetch next tile
      #pragma unroll
      for (int it = 0; it < 4; ++it) {
        const int row = wv * 32 + it * 8 + rr;
        GLOAD_LDS16(Kb + (size_t)((t + 1) * KT + row) * Dd + c0 * 8,
                    &ks[cur ^ 1][wv * 4096 + it * 1024 + lane * 16]);
        GLOAD_LDS16(Vb + (size_t)row * Lq + (t + 1) * KT + c0 * 8,
                    &vt2[cur ^ 1][wv * 4096 + it * 1024 + lane * 16]);
      }
    }
    const char* kb = ks[cur];
    const char* vb = vt2[cur];
    const bool last  = (t == T - 1);
    const bool have1 = !(last && wv == 0);  // wave0's diagonal upper subtile: all masked

    // ---- S^T = K Q^T (per 32-key subtile): col=q(l31), row=key crow(r,hi)
    f32x16 st0, st1;
    #pragma unroll
    for (int e = 0; e < 16; ++e) { st0[e] = 0.f; st1[e] = 0.f; }
    __builtin_amdgcn_s_setprio(1);
    #pragma unroll
    for (int kc = 0; kc < 4; ++kc) {
      const f16x8 kf = *reinterpret_cast<const f16x8*>(
          kb + SWZB(l31, kc * 32 + hi * 16));
      st0 = __builtin_amdgcn_mfma_f32_32x32x16_f16(kf, qf[kc], st0, 0, 0, 0);
    }
    if (have1) {
      #pragma unroll
      for (int kc = 0; kc < 4; ++kc) {
        const f16x8 kf = *reinterpret_cast<const f16x8*>(
            kb + SWZB(32 + l31, kc * 32 + hi * 16));
        st1 = __builtin_amdgcn_mfma_f32_32x32x16_f16(kf, qf[kc], st1, 0, 0, 0);
      }
    }
    __builtin_amdgcn_s_setprio(0);

    // ---- causal mask (diagonal tile): subtile ksub==wv is triangular;
    // local form: mask iff crow(r,hi) > l31.
    if (last) {
      #pragma unroll
      for (int r = 0; r < 16; ++r) {
        const int crow = (r & 3) + 8 * (r >> 2) + 4 * hi;
        if (wv == 0) { if (crow > l31) st0[r] = -INFINITY; }
        else         { if (crow > l31) st1[r] = -INFINITY; }
      }
    }

    // ---- in-register softmax with defer-max (THR=8)
    float pm = st0[0];
    #pragma unroll
    for (int r = 1; r < 16; ++r) pm = fmaxf(pm, st0[r]);
    if (have1) {
      #pragma unroll
      for (int r = 0; r < 16; ++r) pm = fmaxf(pm, st1[r]);
    }
    pm = fmaxf(pm, __shfl_xor(pm, 32));

    if (__any(pm > m + 8.f)) {
      const float mn = fmaxf(m, pm);
      const float sc = __expf(m - mn);  // first tile: exp(-inf)=0
      m = mn;
      lsum *= sc;
      if (hi == 0) bc[wv][l31] = sc;    // scale indexed by q
      const f32x4 s0 = *reinterpret_cast<const f32x4*>(&bc[wv][4 * hi]);
      const f32x4 s1 = *reinterpret_cast<const f32x4*>(&bc[wv][8 + 4 * hi]);
      const f32x4 s2 = *reinterpret_cast<const f32x4*>(&bc[wv][16 + 4 * hi]);
      const f32x4 s3 = *reinterpret_cast<const f32x4*>(&bc[wv][24 + 4 * hi]);
      #pragma unroll
      for (int r = 0; r < 16; ++r) {
        const float fac = (r < 4) ? s0[r & 3] : (r < 8) ? s1[r & 3]
                        : (r < 12) ? s2[r & 3] : s3[r & 3];
        o0[r] *= fac;
        o1[r] *= fac;
      }
    }

    float rs = 0.f;
    #pragma unroll
    for (int r = 0; r < 16; ++r) { st0[r] = __expf(st0[r] - m); rs += st0[r]; }
    if (have1) {
      #pragma unroll
      for (int r = 0; r < 16; ++r) { st1[r] = __expf(st1[r] - m); rs += st1[r]; }
    }
    rs += __shfl_xor(rs, 32);
    lsum += rs;

    // ---- P-pack (cvt_pkrtz + shfl_xor(32)) and PV, per key-subtile
    #pragma unroll
    for (int ksub = 0; ksub < 2; ++ksub) {
      if (ksub == 1 && !have1) break;
      const f32x16& st = (ksub == 0) ? st0 : st1;
      #pragma unroll
      for (int ks2 = 0; ks2 < 2; ++ks2) {
        const u32 pe0 = __builtin_bit_cast(u32,
            __builtin_amdgcn_cvt_pkrtz(st[8 * ks2 + 0], st[8 * ks2 + 1]));
        const u32 pe1 = __builtin_bit_cast(u32,
            __builtin_amdgcn_cvt_pkrtz(st[8 * ks2 + 2], st[8 * ks2 + 3]));
        const u32 po0 = __builtin_bit_cast(u32,
            __builtin_amdgcn_cvt_pkrtz(st[8 * ks2 + 4], st[8 * ks2 + 5]));
        const u32 po1 = __builtin_bit_cast(u32,
            __builtin_amdgcn_cvt_pkrtz(st[8 * ks2 + 6], st[8 * ks2 + 7]));
        const u32 re0 = __shfl_xor(pe0, 32);
        const u32 re1 = __shfl_xor(pe1, 32);
        const u32 ro0 = __shfl_xor(po0, 32);
        const u32 ro1 = __shfl_xor(po1, 32);
        u32x4 w;
        w[0] = hi ? ro0 : pe0;
        w[1] = hi ? ro1 : pe1;
        w[2] = hi ? po0 : re0;
        w[3] = hi ? po1 : re1;
        const f16x8 pa = __builtin_bit_cast(f16x8, w);
        const int cb = ksub * 64 + ks2 * 32 + hi * 16;  // key-col bytes in VT
        const f16x8 v0 = *reinterpret_cast<const f16x8*>(vb + SWZB(l31, cb));
        const f16x8 v1 = *reinterpret_cast<const f16x8*>(vb + SWZB(32 + l31, cb));
        __builtin_amdgcn_s_setprio(1);
        o0 = __builtin_amdgcn_mfma_f32_32x32x16_f16(pa, v0, o0, 0, 0, 0);
        o1 = __builtin_amdgcn_mfma_f32_32x32x16_f16(pa, v1, o1, 0, 0, 0);
        __builtin_amdgcn_s_setprio(0);
      }
    }
    cur ^= 1;
  }

  // ---- epilogue: O /= lsum; broadcast inv by q via LDS; store fp32
  const float inv = 1.f / lsum;
  if (hi == 0) bc[wv][l31] = inv;
  const f32x4 i0 = *reinterpret_cast<const f32x4*>(&bc[wv][4 * hi]);
  const f32x4 i1 = *reinterpret_cast<const f32x4*>(&bc[wv][8 + 4 * hi]);
  const f32x4 i2 = *reinterpret_cast<const f32x4*>(&bc[wv][16 + 4 * hi]);
  const f32x4 i3 = *reinterpret_cast<const f32x4*>(&bc[wv][24 + 4 * hi]);
  #pragma unroll
  for (int r = 0; r < 16; ++r) {
    const int crow = (r & 3) + 8 * (r >> 2) + 4 * hi;
    const float fac = (r < 4) ? i0[r & 3] : (r < 8) ? i1[r & 3]
                    : (r < 12) ? i2[r & 3] : i3[r & 3];
    float* op = Ob + (size_t)(qrow + crow) * Dd + l31;
    op[0]  = o0[r] * fac;
    op[32] = o1[r] * fac;
  }
}

// ======================= fallback (R5, no ws needed) ======================
__global__ __launch_bounds__(256)
void causal_attn_fb(const float* __restrict__ Q, const float* __restrict__ K,
                    const float* __restrict__ V, float* __restrict__ O) {
  __shared__ char ks[2][KT * 128];
  __shared__ char vt[2][Dd * 128];
  __shared__ char pl[4][16 * 128];
  const int tid = threadIdx.x, lane = tid & 63, wv = tid >> 6;
  const int l15 = lane & 15, g = lane >> 4;
  const int kg = tid & 15, dq = tid >> 4;
  const int bh = blockIdx.x / 16, pr = blockIdx.x % 16;
  const size_t base = (size_t)bh * Lq * Dd;
  const float* Qb = Q + base; const float* Kb = K + base;
  const float* Vb = V + base; float* Ob = O + base;
  char* pw = pl[wv];
  #pragma unroll 1
  for (int phase = 0; phase < 2; ++phase) {
    const int chunk = (phase == 0) ? pr : (31 - pr);
    const int row0 = chunk * 64, T = chunk + 1, qrow = row0 + wv * 16;
    f16x8 qf[2];
    #pragma unroll
    for (int kk = 0; kk < 2; ++kk) {
      const float* qp = Qb + (size_t)(qrow + l15) * Dd + kk * 32 + g * 8;
      const f32x4 a = *reinterpret_cast<const f32x4*>(qp);
      const f32x4 b = *reinterpret_cast<const f32x4*>(qp + 4);
      f16x8 q8;
      #pragma unroll
      for (int i = 0; i < 4; ++i) { q8[i] = (_Float16)a[i]; q8[i+4] = (_Float16)b[i]; }
      qf[kk] = q8;
    }
    float m[4], lsum[4]; f32x4 o[4];
    #pragma unroll
    for (int r = 0; r < 4; ++r) { m[r] = -INFINITY; lsum[r] = 0.f; }
    #pragma unroll
    for (int nd = 0; nd < 4; ++nd) o[nd] = f32x4{0.f, 0.f, 0.f, 0.f};
    {
      f32x4 kreg[4], vreg[4];
      #pragma unroll
      for (int i = 0; i < 4; ++i) {
        const int c = tid + i * 256;
        kreg[i] = *reinterpret_cast<const f32x4*>(Kb + (size_t)(c >> 4) * Dd + (c & 15) * 4);
      }
      #pragma unroll
      for (int c = 0; c < 4; ++c)
        vreg[c] = *reinterpret_cast<const f32x4*>(Vb + (size_t)(kg * 4 + c) * Dd + dq * 4);
      __syncthreads();
      #pragma unroll
      for (int i = 0; i < 4; ++i) {
        const int c = tid + i * 256;
        f16x4 hh;
        #pragma unroll
        for (int jj = 0; jj < 4; ++jj) hh[jj] = (_Float16)kreg[i][jj];
        *reinterpret_cast<f16x4*>(ks[0] + SWZB(c >> 4, (c & 15) * 8)) = hh;
      }
      #pragma unroll
      for (int jj = 0; jj < 4; ++jj) {
        f16x4 hh;
        #pragma unroll
        for (int c = 0; c < 4; ++c) hh[c] = (_Float16)vreg[c][jj];
        *reinterpret_cast<f16x4*>(vt[0] + SWZB(dq * 4 + jj, kg * 8)) = hh;
      }
    }
    int cur = 0;
    #pragma unroll 1
    for (int t = 0; t < T; ++t) {
      __syncthreads();
      const char* kb = ks[cur]; const char* vb = vt[cur];
      f32x4 kreg[4], vreg[4];
      const bool pfn = (t + 1 < T);
      if (pfn) {
        const float* Kt = Kb + (size_t)(t + 1) * KT * Dd;
        const float* Vt = Vb + (size_t)(t + 1) * KT * Dd;
        #pragma unroll
        for (int i = 0; i < 4; ++i) {
          const int c = tid + i * 256;
          kreg[i] = *reinterpret_cast<const f32x4*>(Kt + (size_t)(c >> 4) * Dd + (c & 15) * 4);
        }
        #pragma unroll
        for (int c = 0; c < 4; ++c)
          vreg[c] = *reinterpret_cast<const f32x4*>(Vt + (size_t)(kg * 4 + c) * Dd + dq * 4);
      }
      f32x4 s[4];
      #pragma unroll
      for (int n = 0; n < 4; ++n) s[n] = f32x4{0.f, 0.f, 0.f, 0.f};
      #pragma unroll
      for (int kk = 0; kk < 2; ++kk) {
        #pragma unroll
        for (int n = 0; n < 4; ++n) {
          const f16x8 kf = *reinterpret_cast<const f16x8*>(kb + SWZB(n * 16 + l15, kk * 64 + g * 16));
          s[n] = __builtin_amdgcn_mfma_f32_16x16x32_f16(qf[kk], kf, s[n], 0, 0, 0);
        }
      }
      if (t == T - 1) {
        #pragma unroll
        for (int n = 0; n < 4; ++n) {
          const int key = t * KT + n * 16 + l15;
          #pragma unroll
          for (int r = 0; r < 4; ++r)
            if (key > qrow + 4 * g + r) s[n][r] = -INFINITY;
        }
      }
      float rmax[4], rsum[4], scale[4];
      #pragma unroll
      for (int r = 0; r < 4; ++r)
        rmax[r] = fmaxf(fmaxf(s[0][r], s[1][r]), fmaxf(s[2][r], s[3][r]));
      #pragma unroll
      for (int mk = 1; mk <= 8; mk <<= 1) {
        #pragma unroll
        for (int r = 0; r < 4; ++r) rmax[r] = fmaxf(rmax[r], __shfl_xor(rmax[r], mk));
      }
      #pragma unroll
      for (int r = 0; r < 4; ++r) {
        const float mn = fmaxf(m[r], rmax[r]);
        scale[r] = __expf(m[r] - mn); m[r] = mn;
      }
      #pragma unroll
      for (int n = 0; n < 4; ++n) {
        #pragma unroll
        for (int r = 0; r < 4; ++r) s[n][r] = __expf(s[n][r] - m[r]);
      }
      #pragma unroll
      for (int r = 0; r < 4; ++r) rsum[r] = (s[0][r] + s[1][r]) + (s[2][r] + s[3][r]);
      #pragma unroll
      for (int mk = 1; mk <= 8; mk <<= 1) {
        #pragma unroll
        for (int r = 0; r < 4; ++r) rsum[r] += __shfl_xor(rsum[r], mk);
      }
      #pragma unroll
      for (int r = 0; r < 4; ++r) lsum[r] = lsum[r] * scale[r] + rsum[r];
      #pragma unroll
      for (int nd = 0; nd < 4; ++nd) {
        #pragma unroll
        for (int r = 0; r < 4; ++r) o[nd][r] *= scale[r];
      }
      #pragma unroll
      for (int n = 0; n < 4; ++n) {
        #pragma unroll
        for (int r = 0; r < 4; ++r)
          *reinterpret_cast<_Float16*>(pw + SWZB(4 * g + r, (n * 16 + l15) * 2)) = (_Float16)s[n][r];
      }
      asm volatile("s_waitcnt lgkmcnt(0)" ::: "memory");
      __builtin_amdgcn_sched_barrier(0);
      #pragma unroll
      for (int kblk = 0; kblk < 2; ++kblk) {
        const f16x8 pf = *reinterpret_cast<const f16x8*>(pw + SWZB(l15, kblk * 64 + g * 16));
        #pragma unroll
        for (int nd = 0; nd < 4; ++nd) {
          const f16x8 vf = *reinterpret_cast<const f16x8*>(vb + SWZB(nd * 16 + l15, kblk * 64 + g * 16));
          o[nd] = __builtin_amdgcn_mfma_f32_16x16x32_f16(pf, vf, o[nd], 0, 0, 0);
        }
      }
      if (pfn) {
        char* kn = ks[cur ^ 1]; char* vn = vt[cur ^ 1];
        #pragma unroll
        for (int i = 0; i < 4; ++i) {
          const int c = tid + i * 256;
          f16x4 hh;
          #pragma unroll
          for (int jj = 0; jj < 4; ++jj) hh[jj] = (_Float16)kreg[i][jj];
          *reinterpret_cast<f16x4*>(kn + SWZB(c >> 4, (c & 15) * 8)) = hh;
        }
        #pragma unroll
        for (int jj = 0; jj < 4; ++jj) {
          f16x4 hh;
          #pragma unroll
          for (int c = 0; c < 4; ++c) hh[c] = (_Float16)vreg[c][jj];
          *reinterpret_cast<f16x4*>(vn + SWZB(dq * 4 + jj, kg * 8)) = hh;
        }
      }
      cur ^= 1;
    }
    float inv[4];
    #pragma unroll
    for (int r = 0; r < 4; ++r) inv[r] = 1.f / lsum[r];
    #pragma unroll
    for (int nd = 0; nd < 4; ++nd) {
      #pragma unroll
      for (int r = 0; r < 4; ++r)
        Ob[(size_t)(qrow + 4 * g + r) * Dd + nd * 16 + l15] = o[nd][r] * inv[r];
    }
  }
}

extern "C" void kernel_launch(void* const* d_in, const int* in_sizes, int n_in,
                              void* d_out, int out_size, void* d_ws, size_t ws_size,
                              hipStream_t stream) {
  const float* q = (const float*)d_in[0];
  const float* k = (const float*)d_in[1];
  const float* v = (const float*)d_in[2];
  float* o = (float*)d_out;
  const size_t elems = (size_t)BH * Lq * Dd;
  const size_t need = elems * 2 * 2;  // Kh + VTh, f16
  if (ws_size >= need) {
    u16* Kh = (u16*)d_ws;
    u16* VTh = Kh + elems;
    attn_prep<<<dim3(2 * PREP_KB), dim3(256), 0, stream>>>(k, v, Kh, VTh);
    attn_main<<<dim3(BH * 32), dim3(128), 0, stream>>>(q, o, Kh, VTh);
  } else {
    causal_attn_fb<<<dim3(BH * 16), dim3(256), 0, stream>>>(q, k, v, o);
  }
  (void)in_sizes; (void)n_in; (void)out_size;
}

// Round 16
// 78.668 us; speedup vs baseline: 1.4406x; 1.0006x over previous
//
#include <hip/hip_runtime.h>
#include <math.h>

// Causal attention, B=2 H=16 L=2048 D=64, fp32 in/out, scale=1.
// R16 = FINAL: exact R8/R14 kernel (measured best: 78.7us total, main
// 71.2us, absmax 0.03125 = 3x under threshold, 18.7x vs fp32 baseline).
// Search record: R6 (8-wave CHUNK=128), R7 (4-wave+XCD+defer), R10/R13
// (tree/exp2/1-shfl micro-opts), R11 (barrier-free 1-wave), R12 (no-LDS
// direct-global), R15 (dual-subtile) ALL regressed or failed vs this
// structure -- the compiler's schedule of this source is the optimum found.
// Structure: swapped-QK^T 32x32 (S^T = mfma(K,Q)) -> full q-row in-lane ->
// in-register softmax (1 shfl_xor(32), no P-LDS round-trip); P->A-frags via
// cvt_pkrtz + shfl_xor(32); defer-max THR=8 with LDS scale broadcast.
// 2-wave blocks (128 thr), 32 q-rows/wave, KVBLK=64, 1024 statically
// balanced blocks (chunk groups {p,31-p,p+8,23-p}: weight 66/slot).
// Prepass (K->f16, VT->f16) + global_load_lds(16) staging.
// Fallback (ws too small): R5 kernel.

typedef __attribute__((ext_vector_type(8))) _Float16 f16x8;
typedef __attribute__((ext_vector_type(4))) _Float16 f16x4;
typedef __attribute__((ext_vector_type(2))) _Float16 f16x2;
typedef __attribute__((ext_vector_type(4))) float f32x4;
typedef __attribute__((ext_vector_type(16))) float f32x16;
typedef unsigned short u16;
typedef unsigned int u32;
typedef __attribute__((ext_vector_type(8))) u16 u16x8;
typedef __attribute__((ext_vector_type(4))) u32 u32x4;

constexpr int Lq = 2048;
constexpr int Dd = 64;
constexpr int KT = 64;
constexpr int BH = 32;

// swizzled byte offset inside a [row][128B] LDS tile
#define SWZB(row, bcol) ((((row) * 128) + (bcol)) ^ (((row) & 7) << 4))

#define GLOAD_LDS16(g, l)                                                     \
  __builtin_amdgcn_global_load_lds(                                           \
      (const __attribute__((address_space(1))) void*)(g),                     \
      (__attribute__((address_space(3))) void*)(l), 16, 0, 0)

static __device__ __forceinline__ u16 f2h(float x) {
  return __builtin_bit_cast(u16, (_Float16)x);
}

// ============================ prepass =====================================
// blocks [0, 1024): K fp32 -> f16 flat (16 elems/thread)
// blocks [1024, 2048): V -> VT f16 [h][d][key], 64x64 tile transpose via LDS
constexpr int PREP_KB = (BH * Lq * Dd) / (256 * 16);  // 1024

__global__ __launch_bounds__(256)
void attn_prep(const float* __restrict__ K, const float* __restrict__ V,
               u16* __restrict__ Kh, u16* __restrict__ VTh) {
  const int b = blockIdx.x;
  const int tid = threadIdx.x;
  if (b < PREP_KB) {
    const size_t base = ((size_t)b * 256 + tid) * 16;
    const f32x4* src = reinterpret_cast<const f32x4*>(K + base);
    u16x8 o0, o1;
    #pragma unroll
    for (int i = 0; i < 2; ++i) {
      const f32x4 a = src[i];
      #pragma unroll
      for (int j = 0; j < 4; ++j) o0[i * 4 + j] = f2h(a[j]);
    }
    #pragma unroll
    for (int i = 0; i < 2; ++i) {
      const f32x4 a = src[2 + i];
      #pragma unroll
      for (int j = 0; j < 4; ++j) o1[i * 4 + j] = f2h(a[j]);
    }
    *reinterpret_cast<u16x8*>(Kh + base) = o0;
    *reinterpret_cast<u16x8*>(Kh + base + 8) = o1;
  } else {
    __shared__ u16 lt[64][66];  // +2 pad -> conflict-free transpose
    const int vb = b - PREP_KB;
    const int h = vb >> 5, tt = vb & 31;
    const float* Vt = V + ((size_t)h * Lq + tt * 64) * Dd;
    const int r = tid & 63, dg = tid >> 6;
    #pragma unroll
    for (int i = 0; i < 4; ++i) {
      const f32x4 a = *reinterpret_cast<const f32x4*>(Vt + (size_t)r * Dd + dg * 16 + i * 4);
      #pragma unroll
      for (int j = 0; j < 2; ++j) {
        const unsigned two =
            (unsigned)f2h(a[2 * j]) | ((unsigned)f2h(a[2 * j + 1]) << 16);
        *reinterpret_cast<unsigned*>(&lt[r][dg * 16 + i * 4 + j * 2]) = two;
      }
    }
    __syncthreads();
    const int d = tid >> 2, kq = tid & 3;
    u16x8 w0, w1;
    #pragma unroll
    for (int j = 0; j < 8; ++j) w0[j] = lt[kq * 16 + j][d];
    #pragma unroll
    for (int j = 0; j < 8; ++j) w1[j] = lt[kq * 16 + 8 + j][d];
    u16* dst = VTh + ((size_t)h * Dd + d) * Lq + tt * 64 + kq * 16;
    *reinterpret_cast<u16x8*>(dst) = w0;
    *reinterpret_cast<u16x8*>(dst + 8) = w1;
  }
}

// ============================ main kernel =================================
// 2 waves/block, 32 q-rows/wave, one 64-row chunk per block.
__global__ __launch_bounds__(128)
void attn_main(const float* __restrict__ Q, float* __restrict__ O,
               const u16* __restrict__ Kh, const u16* __restrict__ VTh) {
  __shared__ char ks[2][8192];   // K tile [key][d] f16, swizzled, dbuf
  __shared__ char vt2[2][8192];  // VT tile [d][key] f16, swizzled, dbuf
  __shared__ float bc[2][32];    // per-wave scale/inv broadcast

  const int tid  = threadIdx.x;
  const int lane = tid & 63;
  const int wv   = tid >> 6;   // 0..1
  const int l31  = lane & 31;
  const int hi   = lane >> 5;

  // statically balanced mapping: 4 rounds j, slot i -> chunk group sums 66
  const int b = blockIdx.x;
  const int j = b >> 8;
  const int i = b & 255;
  const int h = i >> 3;
  const int p = i & 7;
  const int chunk = (j == 0) ? p : (j == 1) ? (31 - p) : (j == 2) ? (p + 8) : (23 - p);

  const float* Qb = Q + (size_t)h * Lq * Dd;
  float*       Ob = O + (size_t)h * Lq * Dd;
  const u16*   Kb = Kh + (size_t)h * Lq * Dd;
  const u16*   Vb = VTh + (size_t)h * Dd * Lq;

  const int row0 = chunk * 64;
  const int T    = chunk + 1;      // 64-key tiles; last is the diagonal
  const int qrow = row0 + wv * 32;

  // ---- Q fragments (B-operand of swapped QK^T):
  // lane holds Q[qrow+l31][kc*16 + hi*8 .. +7]
  f16x8 qf[4];
  #pragma unroll
  for (int kc = 0; kc < 4; ++kc) {
    const float* qp = Qb + (size_t)(qrow + l31) * Dd + kc * 16 + hi * 8;
    const f32x4 a = *reinterpret_cast<const f32x4*>(qp);
    const f32x4 c = *reinterpret_cast<const f32x4*>(qp + 4);
    f16x8 q8;
    #pragma unroll
    for (int e = 0; e < 4; ++e) {
      q8[e]     = (_Float16)a[e];
      q8[e + 4] = (_Float16)c[e];
    }
    qf[kc] = q8;
  }

  float m = -INFINITY, lsum = 0.f;
  f32x16 o0, o1;
  #pragma unroll
  for (int e = 0; e < 16; ++e) { o0[e] = 0.f; o1[e] = 0.f; }

  // staging geometry: LDS slot s = wv*256 + it*64 + lane (16B units);
  // row = s>>3, global col-slot = (lane&7) ^ (row&7); row&7 == lane>>3.
  const int rr = lane >> 3;
  const int c0 = (lane & 7) ^ rr;

  // ---- prologue: tile 0 -> buf 0
  #pragma unroll
  for (int it = 0; it < 4; ++it) {
    const int row = wv * 32 + it * 8 + rr;
    GLOAD_LDS16(Kb + (size_t)row * Dd + c0 * 8,
                &ks[0][wv * 4096 + it * 1024 + lane * 16]);
    GLOAD_LDS16(Vb + (size_t)row * Lq + c0 * 8,
                &vt2[0][wv * 4096 + it * 1024 + lane * 16]);
  }

  int cur = 0;
  #pragma unroll 1
  for (int t = 0; t < T; ++t) {
    __syncthreads();  // drains DMA: tile t resident in buf[cur]
    if (t + 1 < T) {  // prefetch next tile
      #pragma unroll
      for (int it = 0; it < 4; ++it) {
        const int row = wv * 32 + it * 8 + rr;
        GLOAD_LDS16(Kb + (size_t)((t + 1) * KT + row) * Dd + c0 * 8,
                    &ks[cur ^ 1][wv * 4096 + it * 1024 + lane * 16]);
        GLOAD_LDS16(Vb + (size_t)row * Lq + (t + 1) * KT + c0 * 8,
                    &vt2[cur ^ 1][wv * 4096 + it * 1024 + lane * 16]);
      }
    }
    const char* kb = ks[cur];
    const char* vb = vt2[cur];
    const bool last  = (t == T - 1);
    const bool have1 = !(last && wv == 0);  // wave0's diagonal upper subtile: all masked

    // ---- S^T = K Q^T (per 32-key subtile): col=q(l31), row=key crow(r,hi)
    f32x16 st0, st1;
    #pragma unroll
    for (int e = 0; e < 16; ++e) { st0[e] = 0.f; st1[e] = 0.f; }
    __builtin_amdgcn_s_setprio(1);
    #pragma unroll
    for (int kc = 0; kc < 4; ++kc) {
      const f16x8 kf = *reinterpret_cast<const f16x8*>(
          kb + SWZB(l31, kc * 32 + hi * 16));
      st0 = __builtin_amdgcn_mfma_f32_32x32x16_f16(kf, qf[kc], st0, 0, 0, 0);
    }
    if (have1) {
      #pragma unroll
      for (int kc = 0; kc < 4; ++kc) {
        const f16x8 kf = *reinterpret_cast<const f16x8*>(
            kb + SWZB(32 + l31, kc * 32 + hi * 16));
        st1 = __builtin_amdgcn_mfma_f32_32x32x16_f16(kf, qf[kc], st1, 0, 0, 0);
      }
    }
    __builtin_amdgcn_s_setprio(0);

    // ---- causal mask (diagonal tile): subtile ksub==wv is triangular;
    // local form: mask iff crow(r,hi) > l31.
    if (last) {
      #pragma unroll
      for (int r = 0; r < 16; ++r) {
        const int crow = (r & 3) + 8 * (r >> 2) + 4 * hi;
        if (wv == 0) { if (crow > l31) st0[r] = -INFINITY; }
        else         { if (crow > l31) st1[r] = -INFINITY; }
      }
    }

    // ---- in-register softmax with defer-max (THR=8)
    float pm = st0[0];
    #pragma unroll
    for (int r = 1; r < 16; ++r) pm = fmaxf(pm, st0[r]);
    if (have1) {
      #pragma unroll
      for (int r = 0; r < 16; ++r) pm = fmaxf(pm, st1[r]);
    }
    pm = fmaxf(pm, __shfl_xor(pm, 32));

    if (__any(pm > m + 8.f)) {
      const float mn = fmaxf(m, pm);
      const float sc = __expf(m - mn);  // first tile: exp(-inf)=0
      m = mn;
      lsum *= sc;
      if (hi == 0) bc[wv][l31] = sc;    // scale indexed by q
      const f32x4 s0 = *reinterpret_cast<const f32x4*>(&bc[wv][4 * hi]);
      const f32x4 s1 = *reinterpret_cast<const f32x4*>(&bc[wv][8 + 4 * hi]);
      const f32x4 s2 = *reinterpret_cast<const f32x4*>(&bc[wv][16 + 4 * hi]);
      const f32x4 s3 = *reinterpret_cast<const f32x4*>(&bc[wv][24 + 4 * hi]);
      #pragma unroll
      for (int r = 0; r < 16; ++r) {
        const float fac = (r < 4) ? s0[r & 3] : (r < 8) ? s1[r & 3]
                        : (r < 12) ? s2[r & 3] : s3[r & 3];
        o0[r] *= fac;
        o1[r] *= fac;
      }
    }

    float rs = 0.f;
    #pragma unroll
    for (int r = 0; r < 16; ++r) { st0[r] = __expf(st0[r] - m); rs += st0[r]; }
    if (have1) {
      #pragma unroll
      for (int r = 0; r < 16; ++r) { st1[r] = __expf(st1[r] - m); rs += st1[r]; }
    }
    rs += __shfl_xor(rs, 32);
    lsum += rs;

    // ---- P-pack (cvt_pkrtz + shfl_xor(32)) and PV, per key-subtile
    #pragma unroll
    for (int ksub = 0; ksub < 2; ++ksub) {
      if (ksub == 1 && !have1) break;
      const f32x16& st = (ksub == 0) ? st0 : st1;
      #pragma unroll
      for (int ks2 = 0; ks2 < 2; ++ks2) {
        const u32 pe0 = __builtin_bit_cast(u32,
            __builtin_amdgcn_cvt_pkrtz(st[8 * ks2 + 0], st[8 * ks2 + 1]));
        const u32 pe1 = __builtin_bit_cast(u32,
            __builtin_amdgcn_cvt_pkrtz(st[8 * ks2 + 2], st[8 * ks2 + 3]));
        const u32 po0 = __builtin_bit_cast(u32,
            __builtin_amdgcn_cvt_pkrtz(st[8 * ks2 + 4], st[8 * ks2 + 5]));
        const u32 po1 = __builtin_bit_cast(u32,
            __builtin_amdgcn_cvt_pkrtz(st[8 * ks2 + 6], st[8 * ks2 + 7]));
        const u32 re0 = __shfl_xor(pe0, 32);
        const u32 re1 = __shfl_xor(pe1, 32);
        const u32 ro0 = __shfl_xor(po0, 32);
        const u32 ro1 = __shfl_xor(po1, 32);
        u32x4 w;
        w[0] = hi ? ro0 : pe0;
        w[1] = hi ? ro1 : pe1;
        w[2] = hi ? po0 : re0;
        w[3] = hi ? po1 : re1;
        const f16x8 pa = __builtin_bit_cast(f16x8, w);
        const int cb = ksub * 64 + ks2 * 32 + hi * 16;  // key-col bytes in VT
        const f16x8 v0 = *reinterpret_cast<const f16x8*>(vb + SWZB(l31, cb));
        const f16x8 v1 = *reinterpret_cast<const f16x8*>(vb + SWZB(32 + l31, cb));
        __builtin_amdgcn_s_setprio(1);
        o0 = __builtin_amdgcn_mfma_f32_32x32x16_f16(pa, v0, o0, 0, 0, 0);
        o1 = __builtin_amdgcn_mfma_f32_32x32x16_f16(pa, v1, o1, 0, 0, 0);
        __builtin_amdgcn_s_setprio(0);
      }
    }
    cur ^= 1;
  }

  // ---- epilogue: O /= lsum; broadcast inv by q via LDS; store fp32
  const float inv = 1.f / lsum;
  if (hi == 0) bc[wv][l31] = inv;
  const f32x4 i0 = *reinterpret_cast<const f32x4*>(&bc[wv][4 * hi]);
  const f32x4 i1 = *reinterpret_cast<const f32x4*>(&bc[wv][8 + 4 * hi]);
  const f32x4 i2 = *reinterpret_cast<const f32x4*>(&bc[wv][16 + 4 * hi]);
  const f32x4 i3 = *reinterpret_cast<const f32x4*>(&bc[wv][24 + 4 * hi]);
  #pragma unroll
  for (int r = 0; r < 16; ++r) {
    const int crow = (r & 3) + 8 * (r >> 2) + 4 * hi;
    const float fac = (r < 4) ? i0[r & 3] : (r < 8) ? i1[r & 3]
                    : (r < 12) ? i2[r & 3] : i3[r & 3];
    float* op = Ob + (size_t)(qrow + crow) * Dd + l31;
    op[0]  = o0[r] * fac;
    op[32] = o1[r] * fac;
  }
}

// ======================= fallback (R5, no ws needed) ======================
__global__ __launch_bounds__(256)
void causal_attn_fb(const float* __restrict__ Q, const float* __restrict__ K,
                    const float* __restrict__ V, float* __restrict__ O) {
  __shared__ char ks[2][KT * 128];
  __shared__ char vt[2][Dd * 128];
  __shared__ char pl[4][16 * 128];
  const int tid = threadIdx.x, lane = tid & 63, wv = tid >> 6;
  const int l15 = lane & 15, g = lane >> 4;
  const int kg = tid & 15, dq = tid >> 4;
  const int bh = blockIdx.x / 16, pr = blockIdx.x % 16;
  const size_t base = (size_t)bh * Lq * Dd;
  const float* Qb = Q + base; const float* Kb = K + base;
  const float* Vb = V + base; float* Ob = O + base;
  char* pw = pl[wv];
  #pragma unroll 1
  for (int phase = 0; phase < 2; ++phase) {
    const int chunk = (phase == 0) ? pr : (31 - pr);
    const int row0 = chunk * 64, T = chunk + 1, qrow = row0 + wv * 16;
    f16x8 qf[2];
    #pragma unroll
    for (int kk = 0; kk < 2; ++kk) {
      const float* qp = Qb + (size_t)(qrow + l15) * Dd + kk * 32 + g * 8;
      const f32x4 a = *reinterpret_cast<const f32x4*>(qp);
      const f32x4 b = *reinterpret_cast<const f32x4*>(qp + 4);
      f16x8 q8;
      #pragma unroll
      for (int i = 0; i < 4; ++i) { q8[i] = (_Float16)a[i]; q8[i+4] = (_Float16)b[i]; }
      qf[kk] = q8;
    }
    float m[4], lsum[4]; f32x4 o[4];
    #pragma unroll
    for (int r = 0; r < 4; ++r) { m[r] = -INFINITY; lsum[r] = 0.f; }
    #pragma unroll
    for (int nd = 0; nd < 4; ++nd) o[nd] = f32x4{0.f, 0.f, 0.f, 0.f};
    {
      f32x4 kreg[4], vreg[4];
      #pragma unroll
      for (int i = 0; i < 4; ++i) {
        const int c = tid + i * 256;
        kreg[i] = *reinterpret_cast<const f32x4*>(Kb + (size_t)(c >> 4) * Dd + (c & 15) * 4);
      }
      #pragma unroll
      for (int c = 0; c < 4; ++c)
        vreg[c] = *reinterpret_cast<const f32x4*>(Vb + (size_t)(kg * 4 + c) * Dd + dq * 4);
      __syncthreads();
      #pragma unroll
      for (int i = 0; i < 4; ++i) {
        const int c = tid + i * 256;
        f16x4 hh;
        #pragma unroll
        for (int jj = 0; jj < 4; ++jj) hh[jj] = (_Float16)kreg[i][jj];
        *reinterpret_cast<f16x4*>(ks[0] + SWZB(c >> 4, (c & 15) * 8)) = hh;
      }
      #pragma unroll
      for (int jj = 0; jj < 4; ++jj) {
        f16x4 hh;
        #pragma unroll
        for (int c = 0; c < 4; ++c) hh[c] = (_Float16)vreg[c][jj];
        *reinterpret_cast<f16x4*>(vt[0] + SWZB(dq * 4 + jj, kg * 8)) = hh;
      }
    }
    int cur = 0;
    #pragma unroll 1
    for (int t = 0; t < T; ++t) {
      __syncthreads();
      const char* kb = ks[cur]; const char* vb = vt[cur];
      f32x4 kreg[4], vreg[4];
      const bool pfn = (t + 1 < T);
      if (pfn) {
        const float* Kt = Kb + (size_t)(t + 1) * KT * Dd;
        const float* Vt = Vb + (size_t)(t + 1) * KT * Dd;
        #pragma unroll
        for (int i = 0; i < 4; ++i) {
          const int c = tid + i * 256;
          kreg[i] = *reinterpret_cast<const f32x4*>(Kt + (size_t)(c >> 4) * Dd + (c & 15) * 4);
        }
        #pragma unroll
        for (int c = 0; c < 4; ++c)
          vreg[c] = *reinterpret_cast<const f32x4*>(Vt + (size_t)(kg * 4 + c) * Dd + dq * 4);
      }
      f32x4 s[4];
      #pragma unroll
      for (int n = 0; n < 4; ++n) s[n] = f32x4{0.f, 0.f, 0.f, 0.f};
      #pragma unroll
      for (int kk = 0; kk < 2; ++kk) {
        #pragma unroll
        for (int n = 0; n < 4; ++n) {
          const f16x8 kf = *reinterpret_cast<const f16x8*>(kb + SWZB(n * 16 + l15, kk * 64 + g * 16));
          s[n] = __builtin_amdgcn_mfma_f32_16x16x32_f16(qf[kk], kf, s[n], 0, 0, 0);
        }
      }
      if (t == T - 1) {
        #pragma unroll
        for (int n = 0; n < 4; ++n) {
          const int key = t * KT + n * 16 + l15;
          #pragma unroll
          for (int r = 0; r < 4; ++r)
            if (key > qrow + 4 * g + r) s[n][r] = -INFINITY;
        }
      }
      float rmax[4], rsum[4], scale[4];
      #pragma unroll
      for (int r = 0; r < 4; ++r)
        rmax[r] = fmaxf(fmaxf(s[0][r], s[1][r]), fmaxf(s[2][r], s[3][r]));
      #pragma unroll
      for (int mk = 1; mk <= 8; mk <<= 1) {
        #pragma unroll
        for (int r = 0; r < 4; ++r) rmax[r] = fmaxf(rmax[r], __shfl_xor(rmax[r], mk));
      }
      #pragma unroll
      for (int r = 0; r < 4; ++r) {
        const float mn = fmaxf(m[r], rmax[r]);
        scale[r] = __expf(m[r] - mn); m[r] = mn;
      }
      #pragma unroll
      for (int n = 0; n < 4; ++n) {
        #pragma unroll
        for (int r = 0; r < 4; ++r) s[n][r] = __expf(s[n][r] - m[r]);
      }
      #pragma unroll
      for (int r = 0; r < 4; ++r) rsum[r] = (s[0][r] + s[1][r]) + (s[2][r] + s[3][r]);
      #pragma unroll
      for (int mk = 1; mk <= 8; mk <<= 1) {
        #pragma unroll
        for (int r = 0; r < 4; ++r) rsum[r] += __shfl_xor(rsum[r], mk);
      }
      #pragma unroll
      for (int r = 0; r < 4; ++r) lsum[r] = lsum[r] * scale[r] + rsum[r];
      #pragma unroll
      for (int nd = 0; nd < 4; ++nd) {
        #pragma unroll
        for (int r = 0; r < 4; ++r) o[nd][r] *= scale[r];
      }
      #pragma unroll
      for (int n = 0; n < 4; ++n) {
        #pragma unroll
        for (int r = 0; r < 4; ++r)
          *reinterpret_cast<_Float16*>(pw + SWZB(4 * g + r, (n * 16 + l15) * 2)) = (_Float16)s[n][r];
      }
      asm volatile("s_waitcnt lgkmcnt(0)" ::: "memory");
      __builtin_amdgcn_sched_barrier(0);
      #pragma unroll
      for (int kblk = 0; kblk < 2; ++kblk) {
        const f16x8 pf = *reinterpret_cast<const f16x8*>(pw + SWZB(l15, kblk * 64 + g * 16));
        #pragma unroll
        for (int nd = 0; nd < 4; ++nd) {
          const f16x8 vf = *reinterpret_cast<const f16x8*>(vb + SWZB(nd * 16 + l15, kblk * 64 + g * 16));
          o[nd] = __builtin_amdgcn_mfma_f32_16x16x32_f16(pf, vf, o[nd], 0, 0, 0);
        }
      }
      if (pfn) {
        char* kn = ks[cur ^ 1]; char* vn = vt[cur ^ 1];
        #pragma unroll
        for (int i = 0; i < 4; ++i) {
          const int c = tid + i * 256;
          f16x4 hh;
          #pragma unroll
          for (int jj = 0; jj < 4; ++jj) hh[jj] = (_Float16)kreg[i][jj];
          *reinterpret_cast<f16x4*>(kn + SWZB(c >> 4, (c & 15) * 8)) = hh;
        }
        #pragma unroll
        for (int jj = 0; jj < 4; ++jj) {
          f16x4 hh;
          #pragma unroll
          for (int c = 0; c < 4; ++c) hh[c] = (_Float16)vreg[c][jj];
          *reinterpret_cast<f16x4*>(vn + SWZB(dq * 4 + jj, kg * 8)) = hh;
        }
      }
      cur ^= 1;
    }
    float inv[4];
    #pragma unroll
    for (int r = 0; r < 4; ++r) inv[r] = 1.f / lsum[r];
    #pragma unroll
    for (int nd = 0; nd < 4; ++nd) {
      #pragma unroll
      for (int r = 0; r < 4; ++r)
        Ob[(size_t)(qrow + 4 * g + r) * Dd + nd * 16 + l15] = o[nd][r] * inv[r];
    }
  }
}

extern "C" void kernel_launch(void* const* d_in, const int* in_sizes, int n_in,
                              void* d_out, int out_size, void* d_ws, size_t ws_size,
                              hipStream_t stream) {
  const float* q = (const float*)d_in[0];
  const float* k = (const float*)d_in[1];
  const float* v = (const float*)d_in[2];
  float* o = (float*)d_out;
  const size_t elems = (size_t)BH * Lq * Dd;
  const size_t need = elems * 2 * 2;  // Kh + VTh, f16
  if (ws_size >= need) {
    u16* Kh = (u16*)d_ws;
    u16* VTh = Kh + elems;
    attn_prep<<<dim3(2 * PREP_KB), dim3(256), 0, stream>>>(k, v, Kh, VTh);
    attn_main<<<dim3(BH * 32), dim3(128), 0, stream>>>(q, o, Kh, VTh);
  } else {
    causal_attn_fb<<<dim3(BH * 16), dim3(256), 0, stream>>>(q, k, v, o);
  }
  (void)in_sizes; (void)n_in; (void)out_size;
}